// Round 1
// baseline (1607.354 us; speedup 1.0000x reference)
//
#include <hip/hip_runtime.h>

#define NSEQ 4096
#define DM   512
#define KLR  256
#define HD   512   // H*DH
#define DFF  2048

typedef __attribute__((ext_vector_type(4))) float  f32x4;
typedef __attribute__((ext_vector_type(8))) short  short8;
typedef __attribute__((ext_vector_type(8))) __bf16 bf16x8;

__device__ __forceinline__ short f2bf(float f) {
  unsigned u = __float_as_uint(f);
  u = (u + 0x7fffu + ((u >> 16) & 1u)) >> 16;
  return (short)u;
}

// ---------------- generic bf16 MFMA GEMM ----------------
// C = alpha * op(A)*op(B) + beta*Cf + bscale*bias ; optional relu; writes f32 and/or bf16.
// A: row-major [M, Kd_total] bf16. BTR=true: B given transposed, row-major [N, Kd].
// BTR=false: B row-major [Kd, N] (transpose during LDS staging).
// SK=true: split-K, blockIdx.z = k-chunk, atomicAdd into Cf.
template<int BM, int BN, bool BTR, bool SK>
__global__ __launch_bounds__(256, 2)
void gemm_k(const short* __restrict__ A, int lda, long sA,
            const short* __restrict__ B, int ldb, long sB,
            float* __restrict__ Cf, int ldc, long sCf,
            short* __restrict__ Cb, int ldcb, long sCb,
            const float* __restrict__ bias, float bscale,
            int Kd, float alpha, float beta, int relu, int writeCf)
{
  constexpr int WM = BM / 2, WN = BN / 2, FM = WM / 16, FN = WN / 16;
  const int tid = threadIdx.x;
  const int bz  = blockIdx.z;
  long kbeg = 0;
  if (SK) {
    kbeg = (long)bz * Kd;
  } else {
    A += (long)bz * sA;  B += (long)bz * sB;
    Cf += (long)bz * sCf; Cb += (long)bz * sCb;
  }
  const int bm0 = blockIdx.x * BM, bn0 = blockIdx.y * BN;

  __shared__ __align__(16) short As[BM * 32];
  __shared__ __align__(16) short Bs[BN * 32];

  const int wid = tid >> 6, lane = tid & 63;
  const int wr = wid >> 1, wc = wid & 1;
  const int lrow = lane & 15, lkc = lane >> 4;

  f32x4 acc[FM][FN] = {};
  const int nK = Kd >> 5;
  for (int kt = 0; kt < nK; ++kt) {
    const long kg = kbeg + ((long)kt << 5);
    __syncthreads();
    #pragma unroll
    for (int i = 0; i < (BM * 32) / 2048; ++i) {
      const int flat = ((i << 8) | tid) << 3;
      const int r = flat >> 5, k = flat & 31;
      *(short8*)(As + flat) = *(const short8*)(A + (long)(bm0 + r) * lda + kg + k);
    }
    #pragma unroll
    for (int i = 0; i < (BN * 32) / 2048; ++i) {
      const int flat = ((i << 8) | tid) << 3;
      if (BTR) {
        const int r = flat >> 5, k = flat & 31;
        *(short8*)(Bs + flat) = *(const short8*)(B + (long)(bn0 + r) * ldb + kg + k);
      } else {
        const int k = flat / BN, n = flat % BN;
        short8 v = *(const short8*)(B + (kg + k) * (long)ldb + bn0 + n);
        #pragma unroll
        for (int j = 0; j < 8; ++j) Bs[(n + j) * 32 + k] = v[j];
      }
    }
    __syncthreads();
    bf16x8 af[FM], bfv[FN];
    #pragma unroll
    for (int m = 0; m < FM; ++m)
      af[m] = *(const bf16x8*)(As + ((wr * WM + m * 16 + lrow) << 5) + (lkc << 3));
    #pragma unroll
    for (int n = 0; n < FN; ++n)
      bfv[n] = *(const bf16x8*)(Bs + ((wc * WN + n * 16 + lrow) << 5) + (lkc << 3));
    #pragma unroll
    for (int m = 0; m < FM; ++m)
      #pragma unroll
      for (int n = 0; n < FN; ++n)
        acc[m][n] = __builtin_amdgcn_mfma_f32_16x16x32_bf16(af[m], bfv[n], acc[m][n], 0, 0, 0);
  }

  #pragma unroll
  for (int m = 0; m < FM; ++m) {
    #pragma unroll
    for (int n = 0; n < FN; ++n) {
      const int row0 = bm0 + wr * WM + m * 16 + lkc * 4;
      const int col  = bn0 + wc * WN + n * 16 + lrow;
      #pragma unroll
      for (int r = 0; r < 4; ++r) {
        if (SK) {
          atomicAdd(Cf + (long)(row0 + r) * ldc + col, acc[m][n][r]);
        } else {
          float v = alpha * acc[m][n][r];
          if (beta != 0.f) v += beta * Cf[(long)(row0 + r) * ldc + col];
          if (bias) v += bscale * bias[col];
          if (relu) v = fmaxf(v, 0.f);
          if (writeCf) Cf[(long)(row0 + r) * ldc + col] = v;
          if (Cb) Cb[(long)(row0 + r) * ldcb + col] = f2bf(v);
        }
      }
    }
  }
}

// ---------------- complex layernorm (whitening), writes bf16 [nr; ni] ----------------
__global__ __launch_bounds__(256)
void cln_k(const float* __restrict__ xr, const float* __restrict__ xi, short* __restrict__ out)
{
  const int row  = blockIdx.x * 4 + (threadIdx.x >> 6);
  const int lane = threadIdx.x & 63;
  const float* pr = xr + (long)row * DM + lane * 8;
  const float* pi = xi + (long)row * DM + lane * 8;
  f32x4 a0 = ((const f32x4*)pr)[0], a1 = ((const f32x4*)pr)[1];
  f32x4 b0 = ((const f32x4*)pi)[0], b1 = ((const f32x4*)pi)[1];
  float ar[8], ai[8];
  #pragma unroll
  for (int j = 0; j < 4; ++j) { ar[j] = a0[j]; ar[4 + j] = a1[j]; ai[j] = b0[j]; ai[4 + j] = b1[j]; }
  float sr = 0, si = 0, srr = 0, sii = 0, sri = 0;
  #pragma unroll
  for (int j = 0; j < 8; ++j) {
    sr += ar[j]; si += ai[j];
    srr += ar[j] * ar[j]; sii += ai[j] * ai[j]; sri += ar[j] * ai[j];
  }
  #pragma unroll
  for (int off = 32; off >= 1; off >>= 1) {
    sr  += __shfl_xor(sr, off);  si  += __shfl_xor(si, off);
    srr += __shfl_xor(srr, off); sii += __shfl_xor(sii, off); sri += __shfl_xor(sri, off);
  }
  const float inv512 = 1.f / 512.f;
  float mr = sr * inv512, mi = si * inv512;
  float Crr = srr * inv512 - mr * mr + 1e-5f;
  float Cii = sii * inv512 - mi * mi + 1e-5f;
  float Cri = sri * inv512 - mr * mi;
  float s = sqrtf(fmaxf(Crr * Cii - Cri * Cri, 0.f));
  float t = sqrtf(Crr + Cii + 2.f * s);
  float inv = 1.f / (s * t);
  float Rrr = (Cii + s) * inv, Rii = (Crr + s) * inv, Rri = -Cri * inv;
  short8 vr, vi;
  #pragma unroll
  for (int j = 0; j < 8; ++j) {
    float a = ar[j] - mr, b = ai[j] - mi;
    vr[j] = f2bf(Rrr * a + Rri * b);
    vi[j] = f2bf(Rii * b + Rri * a);
  }
  *(short8*)(out + (long)row * DM + lane * 8) = vr;
  *(short8*)(out + (long)(NSEQ + row) * DM + lane * 8) = vi;
}

// ---------------- f32 [R,C] -> bf16 [C,R] transpose-convert ----------------
__global__ __launch_bounds__(256)
void tcvt_k(const float* __restrict__ in, short* __restrict__ out, int R, int C)
{
  __shared__ float tile[32][33];
  const int bx = blockIdx.x * 32, by = blockIdx.y * 32;
  const int x = threadIdx.x & 31, y = threadIdx.x >> 5;  // y in 0..7
  #pragma unroll
  for (int j = 0; j < 32; j += 8)
    tile[y + j][x] = in[(long)(by + y + j) * C + bx + x];
  __syncthreads();
  #pragma unroll
  for (int j = 0; j < 32; j += 8)
    out[(long)(bx + y + j) * R + by + x] = f2bf(tile[x][y + j]);
}

// ---------------- flat f32 -> bf16 ----------------
__global__ __launch_bounds__(256)
void cvt_k(const float* __restrict__ in, short* __restrict__ out, int n)
{
  const int i = (blockIdx.x * 256 + threadIdx.x) * 4;
  if (i >= n) return;
  f32x4 v = *(const f32x4*)(in + i);
  short o0 = f2bf(v[0]), o1 = f2bf(v[1]), o2 = f2bf(v[2]), o3 = f2bf(v[3]);
  short tmp[4] = {o0, o1, o2, o3};
  *(unsigned long long*)(out + i) = *(unsigned long long*)tmp;
}

extern "C" void kernel_launch(void* const* d_in, const int* in_sizes, int n_in,
                              void* d_out, int out_size, void* d_ws, size_t ws_size,
                              hipStream_t stream)
{
  const float* x_real = (const float*)d_in[0];
  const float* x_imag = (const float*)d_in[1];
  const float* Wq  = (const float*)d_in[2];
  const float* bq  = (const float*)d_in[3];
  const float* Wk  = (const float*)d_in[4];
  const float* bk  = (const float*)d_in[5];
  const float* Wv  = (const float*)d_in[6];
  const float* bv  = (const float*)d_in[7];
  const float* pk  = (const float*)d_in[8];
  const float* pv  = (const float*)d_in[9];
  const float* Wo  = (const float*)d_in[10];
  const float* bo  = (const float*)d_in[11];
  const float* W1r = (const float*)d_in[12];
  const float* W1i = (const float*)d_in[13];
  const float* b1r = (const float*)d_in[14];
  const float* b1i = (const float*)d_in[15];
  const float* W2r = (const float*)d_in[16];
  const float* W2i = (const float*)d_in[17];
  const float* b2r = (const float*)d_in[18];
  const float* b2i = (const float*)d_in[19];

  float* xr = (float*)d_out;
  float* xi = xr + (long)NSEQ * DM;

  char* base = (char*)d_ws;
  size_t off = 0;
  auto alloc = [&](size_t bytes) -> char* {
    char* p = base + off; off += (bytes + 255) & ~(size_t)255; return p;
  };

  short *wqT[2], *wkT[2], *wvT[2], *woT[2], *w1rT[2], *w1iT[2], *w2rT[2], *w2iT[2], *pkT[2], *pvT[2];
  for (int d = 0; d < 2; ++d) {
    wqT[d] = (short*)alloc((size_t)DM * HD * 2);
    wkT[d] = (short*)alloc((size_t)DM * HD * 2);
    wvT[d] = (short*)alloc((size_t)DM * HD * 2);
    woT[d] = (short*)alloc((size_t)HD * DM * 2);
    w1rT[d] = (short*)alloc((size_t)DM * DFF * 2);
    w1iT[d] = (short*)alloc((size_t)DM * DFF * 2);
    w2rT[d] = (short*)alloc((size_t)DFF * DM * 2);
    w2iT[d] = (short*)alloc((size_t)DFF * DM * 2);
    pkT[d] = (short*)alloc((size_t)NSEQ * KLR * 2);
    pvT[d] = (short*)alloc((size_t)NSEQ * KLR * 2);
  }
  short* nrni = (short*)alloc((size_t)2 * NSEQ * DM * 2);
  short* qb   = (short*)alloc((size_t)2 * NSEQ * HD * 2);
  short* kb   = (short*)alloc((size_t)2 * NSEQ * HD * 2);
  short* vb   = (short*)alloc((size_t)2 * NSEQ * HD * 2);
  float* kvf  = (float*)alloc((size_t)4 * KLR * HD * 4);   // keysA,keysB,valsA,valsB f32
  short* keysb  = (short*)alloc((size_t)2 * KLR * HD * 2); // keysA,keysB bf16
  short* valsAT = (short*)alloc((size_t)HD * KLR * 2);     // [512,256]
  short* valsBT = (short*)alloc((size_t)HD * KLR * 2);
  float* Drf = (float*)alloc((size_t)8 * NSEQ * KLR * 4);
  float* Dif = (float*)alloc((size_t)8 * NSEQ * KLR * 4);
  short* Drb = (short*)alloc((size_t)8 * NSEQ * KLR * 2);
  short* Dib = (short*)alloc((size_t)8 * NSEQ * KLR * 2);
  float* orf = (float*)alloc((size_t)NSEQ * HD * 4);
  float* oif = (float*)alloc((size_t)NSEQ * HD * 4);
  short* orb = (short*)alloc((size_t)NSEQ * HD * 2);
  short* oib = (short*)alloc((size_t)NSEQ * HD * 2);
  // FFN aliases (phase-disjoint with Dr/Di):
  float* hrf = Drf; float* hif = Dif;
  short* hrb = Drb; short* hib = Dib;

  if (off > ws_size) return;  // workspace too small — distinctive clean failure

  // launch helper
  auto G = [&](void (*kern)(const short*, int, long, const short*, int, long,
                            float*, int, long, short*, int, long,
                            const float*, float, int, float, float, int, int),
               int gx, int gy, int gz,
               const short* A, int lda, long sA, const short* B, int ldb, long sB,
               float* Cf, int ldc, long sCf, short* Cb, int ldcb, long sCb,
               const float* bias, float bscale, int Kd, float alpha, float beta,
               int relu, int wCf) {
    hipLaunchKernelGGL(kern, dim3(gx, gy, gz), dim3(256), 0, stream,
                       A, lda, sA, B, ldb, sB, Cf, ldc, sCf, Cb, ldcb, sCb,
                       bias, bscale, Kd, alpha, beta, relu, wCf);
  };

  // state init
  hipMemcpyAsync(xr, x_real, (size_t)NSEQ * DM * 4, hipMemcpyDeviceToDevice, stream);
  hipMemcpyAsync(xi, x_imag, (size_t)NSEQ * DM * 4, hipMemcpyDeviceToDevice, stream);

  // weight prep: transpose + bf16
  for (int d = 0; d < 2; ++d) {
    hipLaunchKernelGGL(tcvt_k, dim3(16, 16), dim3(256), 0, stream, Wq + (long)d * DM * HD, wqT[d], DM, HD);
    hipLaunchKernelGGL(tcvt_k, dim3(16, 16), dim3(256), 0, stream, Wk + (long)d * DM * HD, wkT[d], DM, HD);
    hipLaunchKernelGGL(tcvt_k, dim3(16, 16), dim3(256), 0, stream, Wv + (long)d * DM * HD, wvT[d], DM, HD);
    hipLaunchKernelGGL(tcvt_k, dim3(16, 16), dim3(256), 0, stream, Wo + (long)d * HD * DM, woT[d], HD, DM);
    hipLaunchKernelGGL(tcvt_k, dim3(64, 16), dim3(256), 0, stream, W1r + (long)d * DM * DFF, w1rT[d], DM, DFF);
    hipLaunchKernelGGL(tcvt_k, dim3(64, 16), dim3(256), 0, stream, W1i + (long)d * DM * DFF, w1iT[d], DM, DFF);
    hipLaunchKernelGGL(tcvt_k, dim3(16, 64), dim3(256), 0, stream, W2r + (long)d * DFF * DM, w2rT[d], DFF, DM);
    hipLaunchKernelGGL(tcvt_k, dim3(16, 64), dim3(256), 0, stream, W2i + (long)d * DFF * DM, w2iT[d], DFF, DM);
    hipLaunchKernelGGL(tcvt_k, dim3(8, 128), dim3(256), 0, stream, pk + (long)d * NSEQ * KLR, pkT[d], NSEQ, KLR);
    hipLaunchKernelGGL(tcvt_k, dim3(8, 128), dim3(256), 0, stream, pv + (long)d * NSEQ * KLR, pvT[d], NSEQ, KLR);
  }

  const float SC = 0.125f;  // DH^-0.5
  const long qOff = (long)NSEQ * HD;       // offset of "B" (imag-sourced) rows in q/k/v
  const long dStride = (long)NSEQ * KLR;   // per-head stride in Dr/Di

  for (int d = 0; d < 2; ++d) {
    const float* bq_d = bq + d * HD;  const float* bk_d = bk + d * HD;
    const float* bv_d = bv + d * HD;  const float* bo_d = bo + d * DM;
    const float* b1r_d = b1r + d * DFF; const float* b1i_d = b1i + d * DFF;
    const float* b2r_d = b2r + d * DM;  const float* b2i_d = b2i + d * DM;
    float* kvA = kvf;                float* kvB = kvf + (long)KLR * HD;
    float* vvA = kvf + 2L * KLR * HD; float* vvB = kvf + 3L * KLR * HD;

    // ---- attention ----
    hipLaunchKernelGGL(cln_k, dim3(NSEQ / 4), dim3(256), 0, stream, xr, xi, nrni);

    // q/k/v for both real- and imag-sourced inputs: [2N, 512]
    G(gemm_k<128,128,true,false>, 64, 4, 1, nrni, DM, 0, wqT[d], DM, 0,
      nullptr, 0, 0, qb, HD, 0, bq_d, 1.f, DM, 1.f, 0.f, 0, 0);
    G(gemm_k<128,128,true,false>, 64, 4, 1, nrni, DM, 0, wkT[d], DM, 0,
      nullptr, 0, 0, kb, HD, 0, bk_d, 1.f, DM, 1.f, 0.f, 0, 0);
    G(gemm_k<128,128,true,false>, 64, 4, 1, nrni, DM, 0, wvT[d], DM, 0,
      nullptr, 0, 0, vb, HD, 0, bv_d, 1.f, DM, 1.f, 0.f, 0, 0);

    // low-rank projections: keys/vals = pk^T @ k, pv^T @ v  (split-K, f32 atomics)
    hipMemsetAsync(kvf, 0, (size_t)4 * KLR * HD * 4, stream);
    G(gemm_k<128,128,false,true>, 2, 4, 16, pkT[d], NSEQ, 0, kb,        HD, 0,
      kvA, HD, 0, nullptr, 0, 0, nullptr, 0.f, KLR, 1.f, 0.f, 0, 0);
    G(gemm_k<128,128,false,true>, 2, 4, 16, pkT[d], NSEQ, 0, kb + qOff, HD, 0,
      kvB, HD, 0, nullptr, 0, 0, nullptr, 0.f, KLR, 1.f, 0.f, 0, 0);
    G(gemm_k<128,128,false,true>, 2, 4, 16, pvT[d], NSEQ, 0, vb,        HD, 0,
      vvA, HD, 0, nullptr, 0, 0, nullptr, 0.f, KLR, 1.f, 0.f, 0, 0);
    G(gemm_k<128,128,false,true>, 2, 4, 16, pvT[d], NSEQ, 0, vb + qOff, HD, 0,
      vvB, HD, 0, nullptr, 0, 0, nullptr, 0.f, KLR, 1.f, 0.f, 0, 0);
    hipLaunchKernelGGL(cvt_k, dim3(2 * KLR * HD / 1024), dim3(256), 0, stream, kvf, keysb, 2 * KLR * HD);
    hipLaunchKernelGGL(tcvt_k, dim3(HD / 32, KLR / 32), dim3(256), 0, stream, vvA, valsAT, KLR, HD);
    hipLaunchKernelGGL(tcvt_k, dim3(HD / 32, KLR / 32), dim3(256), 0, stream, vvB, valsBT, KLR, HD);

    // dots (complex): Dr = S*(qA kA^T - qB kB^T), Di = S*(qA kB^T + qB kA^T); batched per head
    G(gemm_k<128,128,true,false>, 32, 2, 8, qb,        HD, 64, keysb,               HD, 64,
      Drf, KLR, dStride, nullptr, 0, 0, nullptr, 0.f, 64,  SC, 0.f, 0, 1);
    G(gemm_k<128,128,true,false>, 32, 2, 8, qb + qOff, HD, 64, keysb + (long)KLR*HD, HD, 64,
      Drf, KLR, dStride, Drb, KLR, dStride, nullptr, 0.f, 64, -SC, 1.f, 0, 0);
    G(gemm_k<128,128,true,false>, 32, 2, 8, qb,        HD, 64, keysb + (long)KLR*HD, HD, 64,
      Dif, KLR, dStride, nullptr, 0, 0, nullptr, 0.f, 64,  SC, 0.f, 0, 1);
    G(gemm_k<128,128,true,false>, 32, 2, 8, qb + qOff, HD, 64, keysb,               HD, 64,
      Dif, KLR, dStride, Dib, KLR, dStride, nullptr, 0.f, 64,  SC, 1.f, 0, 0);

    // PV (complex): out_r = Dr vA - Di vB ; out_i = Dr vB + Di vA
    G(gemm_k<128,64,true,false>, 32, 1, 8, Drb, KLR, dStride, valsAT, KLR, 64L * KLR,
      orf, HD, 64, nullptr, 0, 0, nullptr, 0.f, KLR, 1.f, 0.f, 0, 1);
    G(gemm_k<128,64,true,false>, 32, 1, 8, Dib, KLR, dStride, valsBT, KLR, 64L * KLR,
      orf, HD, 64, orb, HD, 64, nullptr, 0.f, KLR, -1.f, 1.f, 0, 0);
    G(gemm_k<128,64,true,false>, 32, 1, 8, Drb, KLR, dStride, valsBT, KLR, 64L * KLR,
      oif, HD, 64, nullptr, 0, 0, nullptr, 0.f, KLR, 1.f, 0.f, 0, 1);
    G(gemm_k<128,64,true,false>, 32, 1, 8, Dib, KLR, dStride, valsAT, KLR, 64L * KLR,
      oif, HD, 64, oib, HD, 64, nullptr, 0.f, KLR, 1.f, 1.f, 0, 0);

    // Wout + residual into state (bias combines to -2*bo for real, +2*bo for imag)
    G(gemm_k<128,128,true,false>, 32, 4, 1, orb, HD, 0, woT[d], HD, 0,
      xr, DM, 0, nullptr, 0, 0, bo_d, -2.f, HD, 1.f, 1.f, 0, 1);
    G(gemm_k<128,128,true,false>, 32, 4, 1, oib, HD, 0, woT[d], HD, 0,
      xi, DM, 0, nullptr, 0, 0, bo_d,  2.f, HD, 1.f, 1.f, 0, 1);

    // ---- FFN ----
    hipLaunchKernelGGL(cln_k, dim3(NSEQ / 4), dim3(256), 0, stream, xr, xi, nrni);

    // hr = relu(nr@W1r - ni@W1i + b1r); hi = relu(nr@W1i + ni@W1r + b1i)
    G(gemm_k<128,128,true,false>, 32, 16, 1, nrni, DM, 0, w1rT[d], DM, 0,
      hrf, DFF, 0, nullptr, 0, 0, b1r_d, 1.f, DM, 1.f, 0.f, 0, 1);
    G(gemm_k<128,128,true,false>, 32, 16, 1, nrni + (long)NSEQ * DM, DM, 0, w1iT[d], DM, 0,
      hrf, DFF, 0, hrb, DFF, 0, nullptr, 0.f, DM, -1.f, 1.f, 1, 0);
    G(gemm_k<128,128,true,false>, 32, 16, 1, nrni, DM, 0, w1iT[d], DM, 0,
      hif, DFF, 0, nullptr, 0, 0, b1i_d, 1.f, DM, 1.f, 0.f, 0, 1);
    G(gemm_k<128,128,true,false>, 32, 16, 1, nrni + (long)NSEQ * DM, DM, 0, w1rT[d], DM, 0,
      hif, DFF, 0, hib, DFF, 0, nullptr, 0.f, DM, 1.f, 1.f, 1, 0);

    // x += h @ W2 (complex) + b2
    G(gemm_k<128,128,true,false>, 32, 4, 1, hrb, DFF, 0, w2rT[d], DFF, 0,
      xr, DM, 0, nullptr, 0, 0, b2r_d, 1.f, DFF, 1.f, 1.f, 0, 1);
    G(gemm_k<128,128,true,false>, 32, 4, 1, hib, DFF, 0, w2iT[d], DFF, 0,
      xr, DM, 0, nullptr, 0, 0, nullptr, 0.f, DFF, -1.f, 1.f, 0, 1);
    G(gemm_k<128,128,true,false>, 32, 4, 1, hrb, DFF, 0, w2iT[d], DFF, 0,
      xi, DM, 0, nullptr, 0, 0, b2i_d, 1.f, DFF, 1.f, 1.f, 0, 1);
    G(gemm_k<128,128,true,false>, 32, 4, 1, hib, DFF, 0, w2rT[d], DFF, 0,
      xi, DM, 0, nullptr, 0, 0, nullptr, 0.f, DFF, 1.f, 1.f, 0, 1);
  }
}

// Round 6
// 1120.204 us; speedup vs baseline: 1.4349x; 1.4349x over previous
//
#include <hip/hip_runtime.h>

#define NSEQ 4096
#define DM   512
#define KLR  256
#define HD   512   // H*DH
#define DFF  2048
#define SCALE 0.125f

typedef __attribute__((ext_vector_type(4))) float  f32x4;
typedef __attribute__((ext_vector_type(8))) short  short8;
typedef __attribute__((ext_vector_type(8))) __bf16 bf16x8;

__device__ __forceinline__ short f2bf(float f) {
  unsigned u = __float_as_uint(f);
  u = (u + 0x7fffu + ((u >> 16) & 1u)) >> 16;
  return (short)u;
}

__device__ __forceinline__ void gload_lds(const short* g, void* ldsbase) {
  __builtin_amdgcn_global_load_lds(
      (const __attribute__((address_space(1))) void*)g,
      (__attribute__((address_space(3))) void*)ldsbase, 16, 0, 0);
}

// ---------------- fast bf16 MFMA GEMM (m97 structure) ----------------
// C = alpha*A*B^T(+beta*Cf)(+bscale*bias)(relu). A [M,K] row-major bf16.
// B given TRANSPOSED: [N,K] row-major bf16. Staging via global_load_lds w=16.
// Non-SK batch z: ptr += bz*stride. SK: bz = (kchunk<<1)|half; atomicAdd f32.
template<int BM, int BN, bool SK>
__global__ __launch_bounds__(256)
void gemm_f(const short* __restrict__ A, int lda, long sA,
            const short* __restrict__ B, int ldb, long sB,
            float* __restrict__ Cf, int ldc, long sCf,
            short* __restrict__ Cb, int ldcb, long sCb,
            short* __restrict__ Cb2, int negCb2,
            const float* __restrict__ bias, float bscale, int rowBias,
            int Kd, float alpha, float beta, int relu, int writeCf)
{
  constexpr int WM = BM / 2, WN = BN / 2, FM = WM / 16, FN = WN / 16;
  constexpr int AISS = (BM * 64) / 4096, BISS = (BN * 64) / 4096;
  const int tid = threadIdx.x, bz = blockIdx.z;
  long kbeg = 0;
  if constexpr (SK) {
    const int half = bz & 1, kc = bz >> 1;
    A += (long)half * sA; B += (long)half * sB; Cf += (long)half * sCf;
    kbeg = (long)kc * Kd;
  } else {
    A += (long)bz * sA; B += (long)bz * sB;
    Cf += (long)bz * sCf; Cb += (long)bz * sCb;
  }
  const int bm0 = blockIdx.x * BM, bn0 = blockIdx.y * BN;
  __shared__ __align__(16) short As[BM * 32];
  __shared__ __align__(16) short Bs[BN * 32];
  const int wid = tid >> 6, lane = tid & 63;
  const int wr = wid >> 1, wc = wid & 1;
  const int lrow = lane & 15, lkc = lane >> 4;

  f32x4 acc[FM][FN] = {};
  const int nK = Kd >> 5;
  for (int kt = 0; kt < nK; ++kt) {
    const long kg = kbeg + ((long)kt << 5);
    if (kt) __syncthreads();   // previous compute done before overwrite
    #pragma unroll
    for (int i = 0; i < AISS; ++i) {
      const int fb = i * 4096 + wid * 1024;
      const int f = fb + lane * 16;
      const int r = f >> 6, e = (f & 63) >> 1;
      gload_lds(A + (long)(bm0 + r) * lda + kg + e, (char*)As + fb);
    }
    #pragma unroll
    for (int i = 0; i < BISS; ++i) {
      const int fb = i * 4096 + wid * 1024;
      const int f = fb + lane * 16;
      const int r = f >> 6, e = (f & 63) >> 1;
      gload_lds(B + (long)(bn0 + r) * ldb + kg + e, (char*)Bs + fb);
    }
    __syncthreads();           // compiler drains vmcnt before s_barrier
    bf16x8 af[FM], bfv[FN];
    #pragma unroll
    for (int m = 0; m < FM; ++m)
      af[m] = *(const bf16x8*)(As + ((wr * WM + m * 16 + lrow) << 5) + (lkc << 3));
    #pragma unroll
    for (int n = 0; n < FN; ++n)
      bfv[n] = *(const bf16x8*)(Bs + ((wc * WN + n * 16 + lrow) << 5) + (lkc << 3));
    #pragma unroll
    for (int m = 0; m < FM; ++m)
      #pragma unroll
      for (int n = 0; n < FN; ++n)
        acc[m][n] = __builtin_amdgcn_mfma_f32_16x16x32_bf16(af[m], bfv[n], acc[m][n], 0, 0, 0);
  }

  #pragma unroll
  for (int m = 0; m < FM; ++m) {
    #pragma unroll
    for (int n = 0; n < FN; ++n) {
      const int row0 = bm0 + wr * WM + m * 16 + lkc * 4;
      const int col  = bn0 + wc * WN + n * 16 + lrow;
      #pragma unroll
      for (int r = 0; r < 4; ++r) {
        if constexpr (SK) {
          atomicAdd(Cf + (long)(row0 + r) * ldc + col, alpha * acc[m][n][r]);
        } else {
          float v = alpha * acc[m][n][r];
          if (beta != 0.f) v += beta * Cf[(long)(row0 + r) * ldc + col];
          if (bias) v += bscale * bias[rowBias ? (row0 + r) : col];
          if (relu) v = fmaxf(v, 0.f);
          if (writeCf) Cf[(long)(row0 + r) * ldc + col] = v;
          if (Cb)  Cb [(long)(row0 + r) * ldcb + col] = f2bf(v);
          if (Cb2) Cb2[(long)(row0 + r) * ldcb + col] = f2bf(negCb2 ? -v : v);
        }
      }
    }
  }
}

// ---------------- complex layernorm -> bf16 cat layout [N, 2*DM] ----------------
__global__ __launch_bounds__(256)
void cln_k(const float* __restrict__ xr, const float* __restrict__ xi, short* __restrict__ ncat)
{
  const int row  = blockIdx.x * 4 + (threadIdx.x >> 6);
  const int lane = threadIdx.x & 63;
  const float* pr = xr + (long)row * DM + lane * 8;
  const float* pi = xi + (long)row * DM + lane * 8;
  f32x4 a0 = ((const f32x4*)pr)[0], a1 = ((const f32x4*)pr)[1];
  f32x4 b0 = ((const f32x4*)pi)[0], b1 = ((const f32x4*)pi)[1];
  float ar[8], ai[8];
  #pragma unroll
  for (int j = 0; j < 4; ++j) { ar[j] = a0[j]; ar[4 + j] = a1[j]; ai[j] = b0[j]; ai[4 + j] = b1[j]; }
  float sr = 0, si = 0, srr = 0, sii = 0, sri = 0;
  #pragma unroll
  for (int j = 0; j < 8; ++j) {
    sr += ar[j]; si += ai[j];
    srr += ar[j] * ar[j]; sii += ai[j] * ai[j]; sri += ar[j] * ai[j];
  }
  #pragma unroll
  for (int off = 32; off >= 1; off >>= 1) {
    sr  += __shfl_xor(sr, off);  si  += __shfl_xor(si, off);
    srr += __shfl_xor(srr, off); sii += __shfl_xor(sii, off); sri += __shfl_xor(sri, off);
  }
  const float inv512 = 1.f / 512.f;
  float mr = sr * inv512, mi = si * inv512;
  float Crr = srr * inv512 - mr * mr + 1e-5f;
  float Cii = sii * inv512 - mi * mi + 1e-5f;
  float Cri = sri * inv512 - mr * mi;
  float s = sqrtf(fmaxf(Crr * Cii - Cri * Cri, 0.f));
  float t = sqrtf(Crr + Cii + 2.f * s);
  float inv = 1.f / (s * t);
  float Rrr = (Cii + s) * inv, Rii = (Crr + s) * inv, Rri = -Cri * inv;
  short8 vr, vi;
  #pragma unroll
  for (int j = 0; j < 8; ++j) {
    float a = ar[j] - mr, b = ai[j] - mi;
    vr[j] = f2bf(Rrr * a + Rri * b);
    vi[j] = f2bf(Rii * b + Rri * a);
  }
  *(short8*)(ncat + (long)row * (2 * DM) + lane * 8) = vr;
  *(short8*)(ncat + (long)row * (2 * DM) + DM + lane * 8) = vi;
}

// ---------------- per-head E = SC*(kA^T vA - kB^T vB), Ei = SC*(kB^T vA + kA^T vB) ----------------
__global__ __launch_bounds__(256)
void e_k(const float* __restrict__ kvf, short* __restrict__ Eo)
{
  const int h = blockIdx.x;
  const int tid = threadIdx.x;
  const int wid = tid >> 6, lane = tid & 63;
  const int wr = wid >> 1, wc = wid & 1;
  const int lrow = lane & 15, lkc = lane >> 4;
  __shared__ short kaT[64 * 32], kbT2[64 * 32], vaT[64 * 32], vbT2[64 * 32];
  const float* kA = kvf + (long)h * 64;
  const float* kB = kA + (long)KLR * HD;
  const float* vA = kB + (long)KLR * HD;
  const float* vB = vA + (long)KLR * HD;
  f32x4 aAA[2][2] = {}, aBB[2][2] = {}, aAB[2][2] = {}, aBA[2][2] = {};
  const int kr = tid >> 3;
  const int dh0 = (tid & 7) * 8;
  for (int kt = 0; kt < 8; ++kt) {
    __syncthreads();
    const long krow = kt * 32 + kr;
    #pragma unroll
    for (int j = 0; j < 8; ++j) {
      const int dh = dh0 + j;
      kaT [dh * 32 + kr] = f2bf(kA[krow * HD + dh]);
      kbT2[dh * 32 + kr] = f2bf(kB[krow * HD + dh]);
      vaT [dh * 32 + kr] = f2bf(vA[krow * HD + dh]);
      vbT2[dh * 32 + kr] = f2bf(vB[krow * HD + dh]);
    }
    __syncthreads();
    bf16x8 fka[2], fkb[2], fva[2], fvb[2];
    #pragma unroll
    for (int m = 0; m < 2; ++m) {
      const int off = ((wr * 32 + m * 16 + lrow) << 5) + (lkc << 3);
      fka[m] = *(const bf16x8*)(kaT + off);
      fkb[m] = *(const bf16x8*)(kbT2 + off);
    }
    #pragma unroll
    for (int n = 0; n < 2; ++n) {
      const int off = ((wc * 32 + n * 16 + lrow) << 5) + (lkc << 3);
      fva[n] = *(const bf16x8*)(vaT + off);
      fvb[n] = *(const bf16x8*)(vbT2 + off);
    }
    #pragma unroll
    for (int m = 0; m < 2; ++m)
      #pragma unroll
      for (int n = 0; n < 2; ++n) {
        aAA[m][n] = __builtin_amdgcn_mfma_f32_16x16x32_bf16(fka[m], fva[n], aAA[m][n], 0, 0, 0);
        aBB[m][n] = __builtin_amdgcn_mfma_f32_16x16x32_bf16(fkb[m], fvb[n], aBB[m][n], 0, 0, 0);
        aAB[m][n] = __builtin_amdgcn_mfma_f32_16x16x32_bf16(fka[m], fvb[n], aAB[m][n], 0, 0, 0);
        aBA[m][n] = __builtin_amdgcn_mfma_f32_16x16x32_bf16(fkb[m], fva[n], aBA[m][n], 0, 0, 0);
      }
  }
  #pragma unroll
  for (int m = 0; m < 2; ++m)
    #pragma unroll
    for (int n = 0; n < 2; ++n) {
      const int row0 = wr * 32 + m * 16 + lkc * 4;
      const int col  = wc * 32 + n * 16 + lrow;
      #pragma unroll
      for (int r = 0; r < 4; ++r) {
        Eo[(long)h * 4096 + (row0 + r) * 64 + col]       = f2bf(SCALE * (aAA[m][n][r] - aBB[m][n][r]));
        Eo[(long)(8 + h) * 4096 + (row0 + r) * 64 + col] = f2bf(SCALE * (aAB[m][n][r] + aBA[m][n][r]));
      }
    }
}

// ---------------- bias vectors: cr = bq@(Fr-Fi) - 2bo ; ci = bq@(Fr+Fi) + 2bo ----------------
__global__ __launch_bounds__(256)
void cvec_k(const float* __restrict__ FrT, const float* __restrict__ FiT,
            const float* __restrict__ bq, const float* __restrict__ bo, float* __restrict__ cv)
{
  const int j = blockIdx.x * 256 + threadIdx.x;  // 0..511
  float sr = 0.f, si = 0.f;
  for (int hd = 0; hd < HD; ++hd) {
    const float b = bq[hd];
    const float fr = FrT[(long)j * HD + hd], fi = FiT[(long)j * HD + hd];
    sr += b * (fr - fi); si += b * (fr + fi);
  }
  cv[j]       = sr - 2.f * bo[j];
  cv[512 + j] = si + 2.f * bo[j];
}

// ---------------- f32 [R,C] -> bf16 transpose, up to two scaled destinations ----------------
__global__ __launch_bounds__(256)
void tcvt2_k(const float* __restrict__ in, short* __restrict__ d1, float s1,
             short* __restrict__ d2, float s2, int R, int C, int ldo)
{
  __shared__ float tile[32][33];
  const int bx = blockIdx.x * 32, by = blockIdx.y * 32;
  const int x = threadIdx.x & 31, y = threadIdx.x >> 5;
  #pragma unroll
  for (int j = 0; j < 32; j += 8)
    tile[y + j][x] = in[(long)(by + y + j) * C + bx + x];
  __syncthreads();
  #pragma unroll
  for (int j = 0; j < 32; j += 8) {
    const float v = tile[x][y + j];
    const long o = (long)(bx + y + j) * ldo + by + x;
    d1[o] = f2bf(s1 * v);
    if (d2) d2[o] = f2bf(s2 * v);
  }
}

// ---------------- flat f32 -> bf16 ----------------
__global__ __launch_bounds__(256)
void cvt_k(const float* __restrict__ in, short* __restrict__ out, int n)
{
  const int i = (blockIdx.x * 256 + threadIdx.x) * 4;
  if (i >= n) return;
  f32x4 v = *(const f32x4*)(in + i);
  short tmp[4] = {f2bf(v[0]), f2bf(v[1]), f2bf(v[2]), f2bf(v[3])};
  *(unsigned long long*)(out + i) = *(unsigned long long*)tmp;
}

extern "C" void kernel_launch(void* const* d_in, const int* in_sizes, int n_in,
                              void* d_out, int out_size, void* d_ws, size_t ws_size,
                              hipStream_t stream)
{
  const float* x_real = (const float*)d_in[0];
  const float* x_imag = (const float*)d_in[1];
  const float* Wq  = (const float*)d_in[2];
  const float* bq  = (const float*)d_in[3];
  const float* Wk  = (const float*)d_in[4];
  const float* bk  = (const float*)d_in[5];
  const float* Wv  = (const float*)d_in[6];
  const float* bv  = (const float*)d_in[7];
  const float* pk  = (const float*)d_in[8];
  const float* pv  = (const float*)d_in[9];
  const float* Wo  = (const float*)d_in[10];
  const float* bo  = (const float*)d_in[11];
  const float* W1r = (const float*)d_in[12];
  const float* W1i = (const float*)d_in[13];
  const float* b1r = (const float*)d_in[14];
  const float* b1i = (const float*)d_in[15];
  const float* W2r = (const float*)d_in[16];
  const float* W2i = (const float*)d_in[17];
  const float* b2r = (const float*)d_in[18];
  const float* b2i = (const float*)d_in[19];

  float* xr = (float*)d_out;
  float* xi = xr + (long)NSEQ * DM;

  char* base = (char*)d_ws;
  size_t off = 0;
  auto alloc = [&](size_t bytes) -> char* {
    char* p = base + off; off += (bytes + 255) & ~(size_t)255; return p;
  };

  short *wkT[2], *wvT[2], *woT[2], *wqB[2], *w1cr[2], *w1ci[2], *w2cr[2], *w2ci[2], *pkT[2], *pvT[2];
  for (int d = 0; d < 2; ++d) {
    wkT[d]  = (short*)alloc((size_t)DM * HD * 2);
    wvT[d]  = (short*)alloc((size_t)DM * HD * 2);
    woT[d]  = (short*)alloc((size_t)HD * DM * 2);
    wqB[d]  = (short*)alloc((size_t)DM * HD * 2);
    w1cr[d] = (short*)alloc((size_t)DFF * 2 * DM * 2);
    w1ci[d] = (short*)alloc((size_t)DFF * 2 * DM * 2);
    w2cr[d] = (short*)alloc((size_t)DM * 2 * DFF * 2);
    w2ci[d] = (short*)alloc((size_t)DM * 2 * DFF * 2);
    pkT[d]  = (short*)alloc((size_t)KLR * NSEQ * 2);
    pvT[d]  = (short*)alloc((size_t)KLR * NSEQ * 2);
  }
  short* ncat = (short*)alloc((size_t)NSEQ * 2 * DM * 2);
  short* kbT  = (short*)alloc((size_t)HD * 2 * NSEQ * 2);
  short* vbT  = (short*)alloc((size_t)HD * 2 * NSEQ * 2);
  float* kvf  = (float*)alloc((size_t)4 * KLR * HD * 4);
  short* Eo   = (short*)alloc((size_t)16 * 64 * 64 * 2);
  float* FrT  = (float*)alloc((size_t)DM * HD * 4);
  float* FiT  = (float*)alloc((size_t)DM * HD * 4);
  short* FrTb = (short*)alloc((size_t)DM * HD * 2);
  short* FiTb = (short*)alloc((size_t)DM * HD * 2);
  short* Bar  = (short*)alloc((size_t)DM * 2 * DM * 2);   // Bapply_r [512,1024]
  short* Bai  = (short*)alloc((size_t)DM * 2 * DM * 2);   // Bapply_i
  float* cv   = (float*)alloc((size_t)1024 * 4);
  short* hcat = (short*)alloc((size_t)NSEQ * 2 * DFF * 2);
  if (off > ws_size) return;

  hipMemcpyAsync(xr, x_real, (size_t)NSEQ * DM * 4, hipMemcpyDeviceToDevice, stream);
  hipMemcpyAsync(xi, x_imag, (size_t)NSEQ * DM * 4, hipMemcpyDeviceToDevice, stream);

  // ---- one-time weight prep ----
  for (int d = 0; d < 2; ++d) {
    tcvt2_k<<<dim3(HD/32, DM/32), 256, 0, stream>>>(Wk + (long)d*DM*HD, wkT[d], 1.f, nullptr, 0.f, DM, HD, DM);
    tcvt2_k<<<dim3(HD/32, DM/32), 256, 0, stream>>>(Wv + (long)d*DM*HD, wvT[d], 1.f, nullptr, 0.f, DM, HD, DM);
    tcvt2_k<<<dim3(DM/32, HD/32), 256, 0, stream>>>(Wo + (long)d*HD*DM, woT[d], 1.f, nullptr, 0.f, HD, DM, HD);
    cvt_k<<<DM*HD/1024, 256, 0, stream>>>(Wq + (long)d*DM*HD, wqB[d], DM*HD);
    tcvt2_k<<<dim3(DFF/32, DM/32), 256, 0, stream>>>(W1r + (long)d*DM*DFF, w1cr[d], 1.f, w1ci[d] + DM, 1.f, DM, DFF, 2*DM);
    tcvt2_k<<<dim3(DFF/32, DM/32), 256, 0, stream>>>(W1i + (long)d*DM*DFF, w1cr[d] + DM, -1.f, w1ci[d], 1.f, DM, DFF, 2*DM);
    tcvt2_k<<<dim3(DM/32, DFF/32), 256, 0, stream>>>(W2r + (long)d*DFF*DM, w2cr[d], 1.f, w2ci[d] + DFF, 1.f, DFF, DM, 2*DFF);
    tcvt2_k<<<dim3(DM/32, DFF/32), 256, 0, stream>>>(W2i + (long)d*DFF*DM, w2cr[d] + DFF, -1.f, w2ci[d], 1.f, DFF, DM, 2*DFF);
    tcvt2_k<<<dim3(KLR/32, NSEQ/32), 256, 0, stream>>>(pk + (long)d*NSEQ*KLR, pkT[d], 1.f, nullptr, 0.f, NSEQ, KLR, NSEQ);
    tcvt2_k<<<dim3(KLR/32, NSEQ/32), 256, 0, stream>>>(pv + (long)d*NSEQ*KLR, pvT[d], 1.f, nullptr, 0.f, NSEQ, KLR, NSEQ);
  }

  for (int d = 0; d < 2; ++d) {
    const float* bk_d = bk + d * HD;   const float* bv_d = bv + d * HD;
    const float* bq_d = bq + d * HD;   const float* bo_d = bo + d * DM;
    const float* b1r_d = b1r + d * DFF; const float* b1i_d = b1i + d * DFF;
    const float* b2r_d = b2r + d * DM;  const float* b2i_d = b2i + d * DM;

    // ---- attention ----
    cln_k<<<NSEQ/4, 256, 0, stream>>>(xr, xi, ncat);

    // kbT/vbT [HD, 2N]: C[hd, n] = sum_d W^T[hd,d] * ncat[n, half*DM + d] + b[hd]
    gemm_f<128,128,false><<<dim3(4, 32, 2), 256, 0, stream>>>(
      wkT[d], DM, 0, ncat, 2*DM, DM, nullptr, 0, 0,
      kbT, 2*NSEQ, NSEQ, nullptr, 0, bk_d, 1.f, 1, DM, 1.f, 0.f, 0, 0);
    gemm_f<128,128,false><<<dim3(4, 32, 2), 256, 0, stream>>>(
      wvT[d], DM, 0, ncat, 2*DM, DM, nullptr, 0, 0,
      vbT, 2*NSEQ, NSEQ, nullptr, 0, bv_d, 1.f, 1, DM, 1.f, 0.f, 0, 0);

    // keys/vals = pk^T kb, pv^T vb  (split-K over 16 chunks, z = (kc<<1)|half)
    hipMemsetAsync(kvf, 0, (size_t)4 * KLR * HD * 4, stream);
    gemm_f<128,128,true><<<dim3(2, 4, 32), 256, 0, stream>>>(
      pkT[d], NSEQ, 0, kbT, 2*NSEQ, NSEQ, kvf, HD, (long)KLR*HD, nullptr, 0, 0,
      nullptr, 0, nullptr, 0.f, 0, 256, 1.f, 0.f, 0, 0);
    gemm_f<128,128,true><<<dim3(2, 4, 32), 256, 0, stream>>>(
      pvT[d], NSEQ, 0, vbT, 2*NSEQ, NSEQ, kvf + 2L*KLR*HD, HD, (long)KLR*HD, nullptr, 0, 0,
      nullptr, 0, nullptr, 0.f, 0, 256, 1.f, 0.f, 0, 0);

    // per-head 64x64 E matrices
    e_k<<<8, 256, 0, stream>>>(kvf, Eo);

    // FrT[dm, h*64+dh] = sum_k Wo[h*64+k, dm] * Er_h[dh, k]   (batched z=8)
    gemm_f<128,64,false><<<dim3(4, 1, 8), 256, 0, stream>>>(
      woT[d], HD, 64, Eo, 64, 4096, FrT, DM, 64, FrTb, DM, 64,
      nullptr, 0, nullptr, 0.f, 0, 64, 1.f, 0.f, 0, 1);
    gemm_f<128,64,false><<<dim3(4, 1, 8), 256, 0, stream>>>(
      woT[d], HD, 64, Eo + 8L*4096, 64, 4096, FiT, DM, 64, FiTb, DM, 64,
      nullptr, 0, nullptr, 0.f, 0, 64, 1.f, 0.f, 0, 1);

    // GrT = FrT @ Wq^T -> Bar[:,0:512](+) and Bai[:,512:1024](+)
    gemm_f<128,128,false><<<dim3(4, 4, 1), 256, 0, stream>>>(
      FrTb, HD, 0, wqB[d], HD, 0, nullptr, 0, 0, Bar, 2*DM, 0,
      Bai + DM, 0, nullptr, 0.f, 0, HD, 1.f, 0.f, 0, 0);
    // GiT -> Bai[:,0:512](+) and Bar[:,512:1024](-)
    gemm_f<128,128,false><<<dim3(4, 4, 1), 256, 0, stream>>>(
      FiTb, HD, 0, wqB[d], HD, 0, nullptr, 0, 0, Bai, 2*DM, 0,
      Bar + DM, 1, nullptr, 0.f, 0, HD, 1.f, 0.f, 0, 0);

    cvec_k<<<2, 256, 0, stream>>>(FrT, FiT, bq_d, bo_d, cv);

    // xr += ncat @ Bar^T + cr ; xi += ncat @ Bai^T + ci
    gemm_f<64,128,false><<<dim3(64, 4, 1), 256, 0, stream>>>(
      ncat, 2*DM, 0, Bar, 2*DM, 0, xr, DM, 0, nullptr, 0, 0,
      nullptr, 0, cv, 1.f, 0, 2*DM, 1.f, 1.f, 0, 1);
    gemm_f<64,128,false><<<dim3(64, 4, 1), 256, 0, stream>>>(
      ncat, 2*DM, 0, Bai, 2*DM, 0, xi, DM, 0, nullptr, 0, 0,
      nullptr, 0, cv + DM, 1.f, 0, 2*DM, 1.f, 1.f, 0, 1);

    // ---- FFN ----
    cln_k<<<NSEQ/4, 256, 0, stream>>>(xr, xi, ncat);

    gemm_f<128,128,false><<<dim3(32, 16, 1), 256, 0, stream>>>(
      ncat, 2*DM, 0, w1cr[d], 2*DM, 0, nullptr, 0, 0, hcat, 2*DFF, 0,
      nullptr, 0, b1r_d, 1.f, 0, 2*DM, 1.f, 0.f, 1, 0);
    gemm_f<128,128,false><<<dim3(32, 16, 1), 256, 0, stream>>>(
      ncat, 2*DM, 0, w1ci[d], 2*DM, 0, nullptr, 0, 0, hcat + DFF, 2*DFF, 0,
      nullptr, 0, b1i_d, 1.f, 0, 2*DM, 1.f, 0.f, 1, 0);

    gemm_f<64,128,false><<<dim3(64, 4, 1), 256, 0, stream>>>(
      hcat, 2*DFF, 0, w2cr[d], 2*DFF, 0, xr, DM, 0, nullptr, 0, 0,
      nullptr, 0, b2r_d, 1.f, 0, 2*DFF, 1.f, 1.f, 0, 1);
    gemm_f<64,128,false><<<dim3(64, 4, 1), 256, 0, stream>>>(
      hcat, 2*DFF, 0, w2ci[d], 2*DFF, 0, xi, DM, 0, nullptr, 0, 0,
      nullptr, 0, b2i_d, 1.f, 0, 2*DFF, 1.f, 1.f, 0, 1);
  }
}

// Round 8
// 909.928 us; speedup vs baseline: 1.7665x; 1.2311x over previous
//
#include <hip/hip_runtime.h>

#define NSEQ 4096
#define DM   512
#define KLR  256
#define HD   512   // H*DH
#define DFF  2048
#define SCALE 0.125f

typedef __attribute__((ext_vector_type(4))) float  f32x4;
typedef __attribute__((ext_vector_type(8))) short  short8;
typedef __attribute__((ext_vector_type(8))) __bf16 bf16x8;

__device__ __forceinline__ short f2bf(float f) {
  unsigned u = __float_as_uint(f);
  u = (u + 0x7fffu + ((u >> 16) & 1u)) >> 16;
  return (short)u;
}

__device__ __forceinline__ void gload_lds(const short* g, void* ldsbase) {
  __builtin_amdgcn_global_load_lds(
      (const __attribute__((address_space(1))) void*)g,
      (__attribute__((address_space(3))) void*)ldsbase, 16, 0, 0);
}

// ---------------- fast bf16 MFMA GEMM (m97 structure + slot swizzle) ----------------
// C = alpha*A*B^T(+beta*Cf)(+bscale*bias)(relu). A [M,K] row-major bf16.
// B TRANSPOSED [N,K] row-major bf16. LDS layout slot-swizzled: slot ^= row&3
// (pre-swizzled global source + swizzled ds_read; fixes 8-way bank conflict).
// Col-split epilogue: col >= colSplit -> Cf += csOff (merged xr/xi outputs).
// SK: bz = (kchunk<<1)|half; atomicAdd f32.
template<int BM, int BN, bool SK>
__global__ __launch_bounds__(256)
void gemm_f(const short* __restrict__ A, int lda, long sA,
            const short* __restrict__ B, int ldb, long sB,
            float* __restrict__ Cf, int ldc, long sCf,
            short* __restrict__ Cb, int ldcb, long sCb,
            short* __restrict__ Cb2, int negCb2,
            const float* __restrict__ bias, float bscale, int rowBias,
            int Kd, float alpha, float beta, int relu, int writeCf,
            int colSplit, long csOff)
{
  constexpr int WM = BM / 2, WN = BN / 2, FM = WM / 16, FN = WN / 16;
  constexpr int AISS = (BM * 64) / 4096, BISS = (BN * 64) / 4096;
  const int tid = threadIdx.x, bz = blockIdx.z;
  long kbeg = 0;
  if constexpr (SK) {
    const int half = bz & 1, kc = bz >> 1;
    A += (long)half * sA; B += (long)half * sB; Cf += (long)half * sCf;
    kbeg = (long)kc * Kd;
  } else {
    A += (long)bz * sA; B += (long)bz * sB;
    Cf += (long)bz * sCf; Cb += (long)bz * sCb;
  }
  const int bm0 = blockIdx.x * BM, bn0 = blockIdx.y * BN;
  __shared__ __align__(16) short As[BM * 32];
  __shared__ __align__(16) short Bs[BN * 32];
  const int wid = tid >> 6, lane = tid & 63;
  const int wr = wid >> 1, wc = wid & 1;
  const int lrow = lane & 15, lkc = lane >> 4;
  const int swz = (lkc ^ (lrow & 3)) << 3;   // swizzled 8-elem slot for ds_read

  f32x4 acc[FM][FN] = {};
  const int nK = Kd >> 5;
  for (int kt = 0; kt < nK; ++kt) {
    const long kg = kbeg + ((long)kt << 5);
    if (kt) __syncthreads();
    #pragma unroll
    for (int i = 0; i < AISS; ++i) {
      const int fb = i * 4096 + wid * 1024;
      const int f = fb + lane * 16;
      const int r = f >> 6, sl = (f >> 4) & 3;
      const int e = ((sl ^ (r & 3)) << 3);     // pre-swizzled global source
      gload_lds(A + (long)(bm0 + r) * lda + kg + e, (char*)As + fb);
    }
    #pragma unroll
    for (int i = 0; i < BISS; ++i) {
      const int fb = i * 4096 + wid * 1024;
      const int f = fb + lane * 16;
      const int r = f >> 6, sl = (f >> 4) & 3;
      const int e = ((sl ^ (r & 3)) << 3);
      gload_lds(B + (long)(bn0 + r) * ldb + kg + e, (char*)Bs + fb);
    }
    __syncthreads();
    bf16x8 af[FM], bfv[FN];
    #pragma unroll
    for (int m = 0; m < FM; ++m)
      af[m] = *(const bf16x8*)(As + ((wr * WM + m * 16 + lrow) << 5) + swz);
    #pragma unroll
    for (int n = 0; n < FN; ++n)
      bfv[n] = *(const bf16x8*)(Bs + ((wc * WN + n * 16 + lrow) << 5) + swz);
    #pragma unroll
    for (int m = 0; m < FM; ++m)
      #pragma unroll
      for (int n = 0; n < FN; ++n)
        acc[m][n] = __builtin_amdgcn_mfma_f32_16x16x32_bf16(af[m], bfv[n], acc[m][n], 0, 0, 0);
  }

  #pragma unroll
  for (int m = 0; m < FM; ++m) {
    #pragma unroll
    for (int n = 0; n < FN; ++n) {
      const int row0 = bm0 + wr * WM + m * 16 + lkc * 4;
      const int col  = bn0 + wc * WN + n * 16 + lrow;
      float* cfp = Cf + ((col >= colSplit) ? csOff : 0);
      #pragma unroll
      for (int r = 0; r < 4; ++r) {
        if constexpr (SK) {
          atomicAdd(Cf + (long)(row0 + r) * ldc + col, alpha * acc[m][n][r]);
        } else {
          float v = alpha * acc[m][n][r];
          if (beta != 0.f) v += beta * cfp[(long)(row0 + r) * ldc + col];
          if (bias) v += bscale * bias[rowBias ? (row0 + r) : col];
          if (relu) v = fmaxf(v, 0.f);
          if (writeCf) cfp[(long)(row0 + r) * ldc + col] = v;
          if (Cb)  Cb [(long)(row0 + r) * ldcb + col] = f2bf(v);
          if (Cb2) Cb2[(long)(row0 + r) * ldcb + col] = f2bf(negCb2 ? -v : v);
        }
      }
    }
  }
}

// ---------------- complex layernorm -> bf16 cat layout [N, 2*DM] ----------------
__global__ __launch_bounds__(256)
void cln_k(const float* __restrict__ xr, const float* __restrict__ xi, short* __restrict__ ncat)
{
  const int row  = blockIdx.x * 4 + (threadIdx.x >> 6);
  const int lane = threadIdx.x & 63;
  const float* pr = xr + (long)row * DM + lane * 8;
  const float* pi = xi + (long)row * DM + lane * 8;
  f32x4 a0 = ((const f32x4*)pr)[0], a1 = ((const f32x4*)pr)[1];
  f32x4 b0 = ((const f32x4*)pi)[0], b1 = ((const f32x4*)pi)[1];
  float ar[8], ai[8];
  #pragma unroll
  for (int j = 0; j < 4; ++j) { ar[j] = a0[j]; ar[4 + j] = a1[j]; ai[j] = b0[j]; ai[4 + j] = b1[j]; }
  float sr = 0, si = 0, srr = 0, sii = 0, sri = 0;
  #pragma unroll
  for (int j = 0; j < 8; ++j) {
    sr += ar[j]; si += ai[j];
    srr += ar[j] * ar[j]; sii += ai[j] * ai[j]; sri += ar[j] * ai[j];
  }
  #pragma unroll
  for (int off = 32; off >= 1; off >>= 1) {
    sr  += __shfl_xor(sr, off);  si  += __shfl_xor(si, off);
    srr += __shfl_xor(srr, off); sii += __shfl_xor(sii, off); sri += __shfl_xor(sri, off);
  }
  const float inv512 = 1.f / 512.f;
  float mr = sr * inv512, mi = si * inv512;
  float Crr = srr * inv512 - mr * mr + 1e-5f;
  float Cii = sii * inv512 - mi * mi + 1e-5f;
  float Cri = sri * inv512 - mr * mi;
  float s = sqrtf(fmaxf(Crr * Cii - Cri * Cri, 0.f));
  float t = sqrtf(Crr + Cii + 2.f * s);
  float inv = 1.f / (s * t);
  float Rrr = (Cii + s) * inv, Rii = (Crr + s) * inv, Rri = -Cri * inv;
  short8 vr, vi;
  #pragma unroll
  for (int j = 0; j < 8; ++j) {
    float a = ar[j] - mr, b = ai[j] - mi;
    vr[j] = f2bf(Rrr * a + Rri * b);
    vi[j] = f2bf(Rii * b + Rri * a);
  }
  *(short8*)(ncat + (long)row * (2 * DM) + lane * 8) = vr;
  *(short8*)(ncat + (long)row * (2 * DM) + DM + lane * 8) = vi;
}

// ---------------- per-head E = SC*(kA^T vA - kB^T vB), Ei = SC*(kB^T vA + kA^T vB) ----------------
__global__ __launch_bounds__(256)
void e_k(const float* __restrict__ kvf, short* __restrict__ Eo)
{
  const int h = blockIdx.x;
  const int tid = threadIdx.x;
  const int wid = tid >> 6, lane = tid & 63;
  const int wr = wid >> 1, wc = wid & 1;
  const int lrow = lane & 15, lkc = lane >> 4;
  __shared__ short kaT[64 * 32], kbT2[64 * 32], vaT[64 * 32], vbT2[64 * 32];
  const float* kA = kvf + (long)h * 64;
  const float* kB = kA + (long)KLR * HD;
  const float* vA = kB + (long)KLR * HD;
  const float* vB = vA + (long)KLR * HD;
  f32x4 aAA[2][2] = {}, aBB[2][2] = {}, aAB[2][2] = {}, aBA[2][2] = {};
  const int kr = tid >> 3;
  const int dh0 = (tid & 7) * 8;
  for (int kt = 0; kt < 8; ++kt) {
    __syncthreads();
    const long krow = kt * 32 + kr;
    #pragma unroll
    for (int j = 0; j < 8; ++j) {
      const int dh = dh0 + j;
      kaT [dh * 32 + kr] = f2bf(kA[krow * HD + dh]);
      kbT2[dh * 32 + kr] = f2bf(kB[krow * HD + dh]);
      vaT [dh * 32 + kr] = f2bf(vA[krow * HD + dh]);
      vbT2[dh * 32 + kr] = f2bf(vB[krow * HD + dh]);
    }
    __syncthreads();
    bf16x8 fka[2], fkb[2], fva[2], fvb[2];
    #pragma unroll
    for (int m = 0; m < 2; ++m) {
      const int off = ((wr * 32 + m * 16 + lrow) << 5) + (lkc << 3);
      fka[m] = *(const bf16x8*)(kaT + off);
      fkb[m] = *(const bf16x8*)(kbT2 + off);
    }
    #pragma unroll
    for (int n = 0; n < 2; ++n) {
      const int off = ((wc * 32 + n * 16 + lrow) << 5) + (lkc << 3);
      fva[n] = *(const bf16x8*)(vaT + off);
      fvb[n] = *(const bf16x8*)(vbT2 + off);
    }
    #pragma unroll
    for (int m = 0; m < 2; ++m)
      #pragma unroll
      for (int n = 0; n < 2; ++n) {
        aAA[m][n] = __builtin_amdgcn_mfma_f32_16x16x32_bf16(fka[m], fva[n], aAA[m][n], 0, 0, 0);
        aBB[m][n] = __builtin_amdgcn_mfma_f32_16x16x32_bf16(fkb[m], fvb[n], aBB[m][n], 0, 0, 0);
        aAB[m][n] = __builtin_amdgcn_mfma_f32_16x16x32_bf16(fka[m], fvb[n], aAB[m][n], 0, 0, 0);
        aBA[m][n] = __builtin_amdgcn_mfma_f32_16x16x32_bf16(fkb[m], fva[n], aBA[m][n], 0, 0, 0);
      }
  }
  #pragma unroll
  for (int m = 0; m < 2; ++m)
    #pragma unroll
    for (int n = 0; n < 2; ++n) {
      const int row0 = wr * 32 + m * 16 + lkc * 4;
      const int col  = wc * 32 + n * 16 + lrow;
      #pragma unroll
      for (int r = 0; r < 4; ++r) {
        Eo[(long)h * 4096 + (row0 + r) * 64 + col]       = f2bf(SCALE * (aAA[m][n][r] - aBB[m][n][r]));
        Eo[(long)(8 + h) * 4096 + (row0 + r) * 64 + col] = f2bf(SCALE * (aAB[m][n][r] + aBA[m][n][r]));
      }
    }
}

// ---------------- bias vectors: cr = bq@(Fr-Fi) - 2bo ; ci = bq@(Fr+Fi) + 2bo ----------------
__global__ __launch_bounds__(256)
void cvec_k(const float* __restrict__ FrT, const float* __restrict__ FiT,
            const float* __restrict__ bq, const float* __restrict__ bo, float* __restrict__ cv)
{
  const int j = blockIdx.x * 256 + threadIdx.x;  // 0..511
  float sr = 0.f, si = 0.f;
  for (int hd = 0; hd < HD; ++hd) {
    const float b = bq[hd];
    const float fr = FrT[(long)j * HD + hd], fi = FiT[(long)j * HD + hd];
    sr += b * (fr - fi); si += b * (fr + fi);
  }
  cv[j]       = sr - 2.f * bo[j];
  cv[512 + j] = si + 2.f * bo[j];
}

// ---------------- f32 [R,C] -> bf16 transpose, two scaled dests, depth-batched ----------------
__global__ __launch_bounds__(256)
void tcvt2_k(const float* __restrict__ in, short* __restrict__ d1, float s1,
             short* __restrict__ d2, float s2, int R, int C, int ldo,
             long inZ, long outZ)
{
  __shared__ float tile[32][33];
  in += (long)blockIdx.z * inZ;
  d1 += (long)blockIdx.z * outZ;
  if (d2) d2 += (long)blockIdx.z * outZ;
  const int bx = blockIdx.x * 32, by = blockIdx.y * 32;
  const int x = threadIdx.x & 31, y = threadIdx.x >> 5;
  #pragma unroll
  for (int j = 0; j < 32; j += 8)
    tile[y + j][x] = in[(long)(by + y + j) * C + bx + x];
  __syncthreads();
  #pragma unroll
  for (int j = 0; j < 32; j += 8) {
    const float v = tile[x][y + j];
    const long o = (long)(bx + y + j) * ldo + by + x;
    d1[o] = f2bf(s1 * v);
    if (d2) d2[o] = f2bf(s2 * v);
  }
}

// ---------------- flat f32 -> bf16 ----------------
__global__ __launch_bounds__(256)
void cvt_k(const float* __restrict__ in, short* __restrict__ out, int n)
{
  const int i = (blockIdx.x * 256 + threadIdx.x) * 4;
  if (i >= n) return;
  f32x4 v = *(const f32x4*)(in + i);
  short tmp[4] = {f2bf(v[0]), f2bf(v[1]), f2bf(v[2]), f2bf(v[3])};
  *(unsigned long long*)(out + i) = *(unsigned long long*)tmp;
}

extern "C" void kernel_launch(void* const* d_in, const int* in_sizes, int n_in,
                              void* d_out, int out_size, void* d_ws, size_t ws_size,
                              hipStream_t stream)
{
  const float* x_real = (const float*)d_in[0];
  const float* x_imag = (const float*)d_in[1];
  const float* Wq  = (const float*)d_in[2];
  const float* bq  = (const float*)d_in[3];
  const float* Wk  = (const float*)d_in[4];
  const float* bk  = (const float*)d_in[5];
  const float* Wv  = (const float*)d_in[6];
  const float* bv  = (const float*)d_in[7];
  const float* pk  = (const float*)d_in[8];
  const float* pv  = (const float*)d_in[9];
  const float* Wo  = (const float*)d_in[10];
  const float* bo  = (const float*)d_in[11];
  const float* W1r = (const float*)d_in[12];
  const float* W1i = (const float*)d_in[13];
  const float* b1r = (const float*)d_in[14];
  const float* b1i = (const float*)d_in[15];
  const float* W2r = (const float*)d_in[16];
  const float* W2i = (const float*)d_in[17];
  const float* b2r = (const float*)d_in[18];
  const float* b2i = (const float*)d_in[19];

  float* xr = (float*)d_out;
  float* xi = xr + (long)NSEQ * DM;
  const int BIG = 1 << 30;
  const long XIOFF = (long)NSEQ * DM - 512;   // col-split offset xr->xi

  char* base = (char*)d_ws;
  size_t off = 0;
  auto alloc = [&](size_t bytes) -> char* {
    char* p = base + off; off += (bytes + 255) & ~(size_t)255; return p;
  };

  // weights (both depths in one buffer; depth stride noted)
  short* wkvT = (short*)alloc((size_t)2 * 1024 * 512 * 2);   // [1024,512], dZ=524288
  short* woT  = (short*)alloc((size_t)2 * DM * HD * 2);      // dZ=262144
  short* wqB  = (short*)alloc((size_t)2 * DM * HD * 2);
  short* w1c  = (short*)alloc((size_t)2 * 4096 * 1024 * 2);  // [4096,1024], dZ=4194304
  short* w2c  = (short*)alloc((size_t)2 * 1024 * 4096 * 2);  // [1024,4096], dZ=4194304
  short* pkT  = (short*)alloc((size_t)2 * KLR * NSEQ * 2);   // dZ=1048576
  short* pvT  = (short*)alloc((size_t)2 * KLR * NSEQ * 2);
  float* bkvcat = (float*)alloc((size_t)2 * 1024 * 4);
  float* b1cat  = (float*)alloc((size_t)2 * 4096 * 4);
  float* b2cat  = (float*)alloc((size_t)2 * 1024 * 4);
  // activations
  short* ncat  = (short*)alloc((size_t)NSEQ * 2 * DM * 2);
  short* kvbT  = (short*)alloc((size_t)1024 * 2 * NSEQ * 2); // rows 0-511 k, 512-1023 v
  float* kvf   = (float*)alloc((size_t)4 * KLR * HD * 4);
  short* Eo    = (short*)alloc((size_t)16 * 64 * 64 * 2);
  float* FrT   = (float*)alloc((size_t)DM * HD * 4);
  float* FiT   = (float*)alloc((size_t)DM * HD * 4);
  short* FrTb  = (short*)alloc((size_t)DM * HD * 2);
  short* FiTb  = (short*)alloc((size_t)DM * HD * 2);
  short* BarBai= (short*)alloc((size_t)1024 * 1024 * 2);     // rows 0-511 Bar, 512-1023 Bai
  float* cv    = (float*)alloc((size_t)1024 * 4);
  short* hcat  = (short*)alloc((size_t)NSEQ * 2 * DFF * 2);  // [4096,4096]
  if (off > ws_size) return;

  hipMemcpyAsync(xr, x_real, (size_t)NSEQ * DM * 4, hipMemcpyDeviceToDevice, stream);
  hipMemcpyAsync(xi, x_imag, (size_t)NSEQ * DM * 4, hipMemcpyDeviceToDevice, stream);

  // ---- one-time weight prep (depth-batched z=2) ----
  tcvt2_k<<<dim3(HD/32, DM/32, 2), 256, 0, stream>>>(Wk, wkvT, 1.f, nullptr, 0.f, DM, HD, DM, (long)DM*HD, 524288);
  tcvt2_k<<<dim3(HD/32, DM/32, 2), 256, 0, stream>>>(Wv, wkvT + 512*512, 1.f, nullptr, 0.f, DM, HD, DM, (long)DM*HD, 524288);
  tcvt2_k<<<dim3(DM/32, HD/32, 2), 256, 0, stream>>>(Wo, woT, 1.f, nullptr, 0.f, HD, DM, HD, (long)HD*DM, 262144);
  cvt_k<<<2*DM*HD/1024, 256, 0, stream>>>(Wq, wqB, 2*DM*HD);
  tcvt2_k<<<dim3(DFF/32, DM/32, 2), 256, 0, stream>>>(W1r, w1c, 1.f, w1c + 2048*1024 + DM, 1.f, DM, DFF, 1024, (long)DM*DFF, 4194304);
  tcvt2_k<<<dim3(DFF/32, DM/32, 2), 256, 0, stream>>>(W1i, w1c + DM, -1.f, w1c + 2048*1024, 1.f, DM, DFF, 1024, (long)DM*DFF, 4194304);
  tcvt2_k<<<dim3(DM/32, DFF/32, 2), 256, 0, stream>>>(W2r, w2c, 1.f, w2c + 512*4096 + DFF, 1.f, DFF, DM, 4096, (long)DFF*DM, 4194304);
  tcvt2_k<<<dim3(DM/32, DFF/32, 2), 256, 0, stream>>>(W2i, w2c + DFF, -1.f, w2c + 512*4096, 1.f, DFF, DM, 4096, (long)DFF*DM, 4194304);
  tcvt2_k<<<dim3(KLR/32, NSEQ/32, 2), 256, 0, stream>>>(pk, pkT, 1.f, nullptr, 0.f, NSEQ, KLR, NSEQ, (long)NSEQ*KLR, 1048576);
  tcvt2_k<<<dim3(KLR/32, NSEQ/32, 2), 256, 0, stream>>>(pv, pvT, 1.f, nullptr, 0.f, NSEQ, KLR, NSEQ, (long)NSEQ*KLR, 1048576);
  for (int d = 0; d < 2; ++d) {
    hipMemcpyAsync(bkvcat + d*1024,       bk + d*HD,  HD*4,  hipMemcpyDeviceToDevice, stream);
    hipMemcpyAsync(bkvcat + d*1024 + 512, bv + d*HD,  HD*4,  hipMemcpyDeviceToDevice, stream);
    hipMemcpyAsync(b1cat + d*4096,        b1r + d*DFF, DFF*4, hipMemcpyDeviceToDevice, stream);
    hipMemcpyAsync(b1cat + d*4096 + 2048, b1i + d*DFF, DFF*4, hipMemcpyDeviceToDevice, stream);
    hipMemcpyAsync(b2cat + d*1024,        b2r + d*DM,  DM*4,  hipMemcpyDeviceToDevice, stream);
    hipMemcpyAsync(b2cat + d*1024 + 512,  b2i + d*DM,  DM*4,  hipMemcpyDeviceToDevice, stream);
  }

  for (int d = 0; d < 2; ++d) {
    const short* wkvT_d = wkvT + (long)d * 524288;
    const short* woT_d  = woT  + (long)d * 262144;
    const short* wqB_d  = wqB  + (long)d * 262144;
    const short* w1c_d  = w1c  + (long)d * 4194304;
    const short* w2c_d  = w2c  + (long)d * 4194304;
    const short* pkT_d  = pkT  + (long)d * 1048576;
    const short* pvT_d  = pvT  + (long)d * 1048576;
    const float* bq_d = bq + d * HD;   const float* bo_d = bo + d * DM;
    short* vbT = kvbT + (long)512 * 2 * NSEQ;

    // ---- attention ----
    cln_k<<<NSEQ/4, 256, 0, stream>>>(xr, xi, ncat);

    // merged k|v projection: kvbT[row, z*N + n], rows 0-511=k, 512-1023=v
    gemm_f<128,128,false><<<dim3(8, 32, 2), 256, 0, stream>>>(
      wkvT_d, 512, 0, ncat, 2*DM, DM, nullptr, 0, 0,
      kvbT, 2*NSEQ, NSEQ, nullptr, 0, bkvcat + d*1024, 1.f, 1, 512, 1.f, 0.f, 0, 0, BIG, 0);

    // keys/vals = pk^T k, pv^T v  (split-K, z = (kc<<1)|half)
    hipMemsetAsync(kvf, 0, (size_t)4 * KLR * HD * 4, stream);
    gemm_f<128,128,true><<<dim3(2, 4, 32), 256, 0, stream>>>(
      pkT_d, NSEQ, 0, kvbT, 2*NSEQ, NSEQ, kvf, HD, (long)KLR*HD, nullptr, 0, 0,
      nullptr, 0, nullptr, 0.f, 0, 256, 1.f, 0.f, 0, 0, BIG, 0);
    gemm_f<128,128,true><<<dim3(2, 4, 32), 256, 0, stream>>>(
      pvT_d, NSEQ, 0, vbT, 2*NSEQ, NSEQ, kvf + 2L*KLR*HD, HD, (long)KLR*HD, nullptr, 0, 0,
      nullptr, 0, nullptr, 0.f, 0, 256, 1.f, 0.f, 0, 0, BIG, 0);

    // per-head 64x64 E matrices
    e_k<<<8, 256, 0, stream>>>(kvf, Eo);

    // F = E @ Wo (batched per head)
    gemm_f<128,64,false><<<dim3(4, 1, 8), 256, 0, stream>>>(
      woT_d, HD, 64, Eo, 64, 4096, FrT, DM, 64, FrTb, DM, 64,
      nullptr, 0, nullptr, 0.f, 0, 64, 1.f, 0.f, 0, 1, BIG, 0);
    gemm_f<128,64,false><<<dim3(4, 1, 8), 256, 0, stream>>>(
      woT_d, HD, 64, Eo + 8L*4096, 64, 4096, FiT, DM, 64, FiTb, DM, 64,
      nullptr, 0, nullptr, 0.f, 0, 64, 1.f, 0.f, 0, 1, BIG, 0);

    // G: BarBai rows 0-511 = Bar, rows 512-1023 = Bai
    gemm_f<128,128,false><<<dim3(4, 4, 1), 256, 0, stream>>>(
      FrTb, HD, 0, wqB_d, HD, 0, nullptr, 0, 0, BarBai, 2*DM, 0,
      BarBai + 512*1024 + DM, 0, nullptr, 0.f, 0, HD, 1.f, 0.f, 0, 0, BIG, 0);
    gemm_f<128,128,false><<<dim3(4, 4, 1), 256, 0, stream>>>(
      FiTb, HD, 0, wqB_d, HD, 0, nullptr, 0, 0, BarBai + 512*1024, 2*DM, 0,
      BarBai + DM, 1, nullptr, 0.f, 0, HD, 1.f, 0.f, 0, 0, BIG, 0);

    cvec_k<<<2, 256, 0, stream>>>(FrT, FiT, bq_d, bo_d, cv);

    // merged apply: cols 0-511 -> xr, 512-1023 -> xi (col-split epilogue)
    gemm_f<64,128,false><<<dim3(64, 8, 1), 256, 0, stream>>>(
      ncat, 2*DM, 0, BarBai, 2*DM, 0, xr, DM, 0, nullptr, 0, 0,
      nullptr, 0, cv, 1.f, 0, 2*DM, 1.f, 1.f, 0, 1, 512, XIOFF);

    // ---- FFN ----
    cln_k<<<NSEQ/4, 256, 0, stream>>>(xr, xi, ncat);

    // merged FFN1: N=4096 (hr cols 0-2047, hi cols 2048-4095 -> hcat directly)
    gemm_f<128,128,false><<<dim3(32, 32, 1), 256, 0, stream>>>(
      ncat, 2*DM, 0, w1c_d, 2*DM, 0, nullptr, 0, 0, hcat, 2*DFF, 0,
      nullptr, 0, b1cat + d*4096, 1.f, 0, 2*DM, 1.f, 0.f, 1, 0, BIG, 0);

    // merged FFN2: cols 0-511 -> xr, 512-1023 -> xi
    gemm_f<64,128,false><<<dim3(64, 8, 1), 256, 0, stream>>>(
      hcat, 2*DFF, 0, w2c_d, 2*DFF, 0, xr, DM, 0, nullptr, 0, 0,
      nullptr, 0, b2cat + d*1024, 1.f, 0, 2*DFF, 1.f, 1.f, 0, 1, 512, XIOFF);
  }
}

// Round 9
// 852.526 us; speedup vs baseline: 1.8854x; 1.0673x over previous
//
#include <hip/hip_runtime.h>

#define NSEQ 4096
#define DM   512
#define KLR  256
#define HD   512   // H*DH
#define DFF  2048
#define SCALE 0.125f

typedef __attribute__((ext_vector_type(4))) float  f32x4;
typedef __attribute__((ext_vector_type(8))) short  short8;
typedef __attribute__((ext_vector_type(8))) __bf16 bf16x8;

__device__ __forceinline__ short f2bf(float f) {
  unsigned u = __float_as_uint(f);
  u = (u + 0x7fffu + ((u >> 16) & 1u)) >> 16;
  return (short)u;
}

__device__ __forceinline__ void gload_lds(const short* g, void* ldsbase) {
  __builtin_amdgcn_global_load_lds(
      (const __attribute__((address_space(1))) void*)g,
      (__attribute__((address_space(3))) void*)ldsbase, 16, 0, 0);
}

// ---------------- fast bf16 MFMA GEMM (m97 structure) ----------------
// C = alpha*A*B^T(+beta*Cf)(+bscale*bias)(relu). A [M,K] row-major bf16.
// B TRANSPOSED [N,K] row-major bf16. global_load_lds w=16 staging (linear:
// LDS row-read serialization is the BW floor; swizzle proven no-op r8).
// Col-split epilogue: col >= colSplit -> Cf += csOff (merged xr/xi outputs).
// SK: half = bz%skH, kchunk = bz/skH; atomicAdd f32 (+bias once at kc==0).
// negMask: bit bz -> negate Cb2 write for that batch. sCb2 may be negative.
template<int BM, int BN, bool SK>
__global__ __launch_bounds__(256)
void gemm_f(const short* __restrict__ A, int lda, long sA,
            const short* __restrict__ B, int ldb, long sB,
            float* __restrict__ Cf, int ldc, long sCf,
            short* __restrict__ Cb, int ldcb, long sCb,
            short* __restrict__ Cb2, long sCb2, int negMask,
            const float* __restrict__ bias, float bscale, int rowBias,
            int Kd, float alpha, float beta, int relu, int writeCf,
            int colSplit, long csOff, int skH)
{
  constexpr int WM = BM / 2, WN = BN / 2, FM = WM / 16, FN = WN / 16;
  constexpr int AISS = (BM * 64) / 4096, BISS = (BN * 64) / 4096;
  const int tid = threadIdx.x, bz = blockIdx.z;
  long kbeg = 0;
  int kc = 0;
  if constexpr (SK) {
    const int half = bz % skH; kc = bz / skH;
    A += (long)half * sA; B += (long)half * sB; Cf += (long)half * sCf;
    kbeg = (long)kc * Kd;
  } else {
    A += (long)bz * sA; B += (long)bz * sB;
    Cf += (long)bz * sCf; Cb += (long)bz * sCb;
    if (Cb2) Cb2 += (long)bz * sCb2;
  }
  const int bm0 = blockIdx.x * BM, bn0 = blockIdx.y * BN;
  __shared__ __align__(16) short As[BM * 32];
  __shared__ __align__(16) short Bs[BN * 32];
  const int wid = tid >> 6, lane = tid & 63;
  const int wr = wid >> 1, wc = wid & 1;
  const int lrow = lane & 15, lkc = lane >> 4;

  f32x4 acc[FM][FN] = {};
  const int nK = Kd >> 5;
  for (int kt = 0; kt < nK; ++kt) {
    const long kg = kbeg + ((long)kt << 5);
    if (kt) __syncthreads();
    #pragma unroll
    for (int i = 0; i < AISS; ++i) {
      const int fb = i * 4096 + wid * 1024;
      const int f = fb + lane * 16;
      const int r = f >> 6, e = (f & 63) >> 1;
      gload_lds(A + (long)(bm0 + r) * lda + kg + e, (char*)As + fb);
    }
    #pragma unroll
    for (int i = 0; i < BISS; ++i) {
      const int fb = i * 4096 + wid * 1024;
      const int f = fb + lane * 16;
      const int r = f >> 6, e = (f & 63) >> 1;
      gload_lds(B + (long)(bn0 + r) * ldb + kg + e, (char*)Bs + fb);
    }
    __syncthreads();
    bf16x8 af[FM], bfv[FN];
    #pragma unroll
    for (int m = 0; m < FM; ++m)
      af[m] = *(const bf16x8*)(As + ((wr * WM + m * 16 + lrow) << 5) + (lkc << 3));
    #pragma unroll
    for (int n = 0; n < FN; ++n)
      bfv[n] = *(const bf16x8*)(Bs + ((wc * WN + n * 16 + lrow) << 5) + (lkc << 3));
    #pragma unroll
    for (int m = 0; m < FM; ++m)
      #pragma unroll
      for (int n = 0; n < FN; ++n)
        acc[m][n] = __builtin_amdgcn_mfma_f32_16x16x32_bf16(af[m], bfv[n], acc[m][n], 0, 0, 0);
  }

  #pragma unroll
  for (int m = 0; m < FM; ++m) {
    #pragma unroll
    for (int n = 0; n < FN; ++n) {
      const int row0 = bm0 + wr * WM + m * 16 + lkc * 4;
      const int col  = bn0 + wc * WN + n * 16 + lrow;
      float* cfp = Cf + ((col >= colSplit) ? csOff : 0);
      #pragma unroll
      for (int r = 0; r < 4; ++r) {
        if constexpr (SK) {
          float v = alpha * acc[m][n][r];
          if (bias && kc == 0) v += bscale * bias[rowBias ? (row0 + r) : col];
          atomicAdd(cfp + (long)(row0 + r) * ldc + col, v);
        } else {
          float v = alpha * acc[m][n][r];
          if (beta != 0.f) v += beta * cfp[(long)(row0 + r) * ldc + col];
          if (bias) v += bscale * bias[rowBias ? (row0 + r) : col];
          if (relu) v = fmaxf(v, 0.f);
          if (writeCf) cfp[(long)(row0 + r) * ldc + col] = v;
          if (Cb)  Cb [(long)(row0 + r) * ldcb + col] = f2bf(v);
          if (Cb2) Cb2[(long)(row0 + r) * ldcb + col] = f2bf(((negMask >> bz) & 1) ? -v : v);
        }
      }
    }
  }
}

// ---------------- complex layernorm -> bf16 cat layout [N, 2*DM] ----------------
__global__ __launch_bounds__(256)
void cln_k(const float* __restrict__ xr, const float* __restrict__ xi, short* __restrict__ ncat)
{
  const int row  = blockIdx.x * 4 + (threadIdx.x >> 6);
  const int lane = threadIdx.x & 63;
  const float* pr = xr + (long)row * DM + lane * 8;
  const float* pi = xi + (long)row * DM + lane * 8;
  f32x4 a0 = ((const f32x4*)pr)[0], a1 = ((const f32x4*)pr)[1];
  f32x4 b0 = ((const f32x4*)pi)[0], b1 = ((const f32x4*)pi)[1];
  float ar[8], ai[8];
  #pragma unroll
  for (int j = 0; j < 4; ++j) { ar[j] = a0[j]; ar[4 + j] = a1[j]; ai[j] = b0[j]; ai[4 + j] = b1[j]; }
  float sr = 0, si = 0, srr = 0, sii = 0, sri = 0;
  #pragma unroll
  for (int j = 0; j < 8; ++j) {
    sr += ar[j]; si += ai[j];
    srr += ar[j] * ar[j]; sii += ai[j] * ai[j]; sri += ar[j] * ai[j];
  }
  #pragma unroll
  for (int off = 32; off >= 1; off >>= 1) {
    sr  += __shfl_xor(sr, off);  si  += __shfl_xor(si, off);
    srr += __shfl_xor(srr, off); sii += __shfl_xor(sii, off); sri += __shfl_xor(sri, off);
  }
  const float inv512 = 1.f / 512.f;
  float mr = sr * inv512, mi = si * inv512;
  float Crr = srr * inv512 - mr * mr + 1e-5f;
  float Cii = sii * inv512 - mi * mi + 1e-5f;
  float Cri = sri * inv512 - mr * mi;
  float s = sqrtf(fmaxf(Crr * Cii - Cri * Cri, 0.f));
  float t = sqrtf(Crr + Cii + 2.f * s);
  float inv = 1.f / (s * t);
  float Rrr = (Cii + s) * inv, Rii = (Crr + s) * inv, Rri = -Cri * inv;
  short8 vr, vi;
  #pragma unroll
  for (int j = 0; j < 8; ++j) {
    float a = ar[j] - mr, b = ai[j] - mi;
    vr[j] = f2bf(Rrr * a + Rri * b);
    vi[j] = f2bf(Rii * b + Rri * a);
  }
  *(short8*)(ncat + (long)row * (2 * DM) + lane * 8) = vr;
  *(short8*)(ncat + (long)row * (2 * DM) + DM + lane * 8) = vi;
}

// ---------------- per-head E = SC*(kA^T vA - kB^T vB), Ei = SC*(kB^T vA + kA^T vB) ----------------
__global__ __launch_bounds__(256)
void e_k(const float* __restrict__ kvf, short* __restrict__ Eo)
{
  const int h = blockIdx.x;
  const int tid = threadIdx.x;
  const int wid = tid >> 6, lane = tid & 63;
  const int wr = wid >> 1, wc = wid & 1;
  const int lrow = lane & 15, lkc = lane >> 4;
  __shared__ short kaT[64 * 32], kbT2[64 * 32], vaT[64 * 32], vbT2[64 * 32];
  const float* kA = kvf + (long)h * 64;
  const float* kB = kA + (long)KLR * HD;
  const float* vA = kB + (long)KLR * HD;
  const float* vB = vA + (long)KLR * HD;
  f32x4 aAA[2][2] = {}, aBB[2][2] = {}, aAB[2][2] = {}, aBA[2][2] = {};
  const int kr = tid >> 3;
  const int dh0 = (tid & 7) * 8;
  for (int kt = 0; kt < 8; ++kt) {
    __syncthreads();
    const long krow = kt * 32 + kr;
    #pragma unroll
    for (int j = 0; j < 8; ++j) {
      const int dh = dh0 + j;
      kaT [dh * 32 + kr] = f2bf(kA[krow * HD + dh]);
      kbT2[dh * 32 + kr] = f2bf(kB[krow * HD + dh]);
      vaT [dh * 32 + kr] = f2bf(vA[krow * HD + dh]);
      vbT2[dh * 32 + kr] = f2bf(vB[krow * HD + dh]);
    }
    __syncthreads();
    bf16x8 fka[2], fkb[2], fva[2], fvb[2];
    #pragma unroll
    for (int m = 0; m < 2; ++m) {
      const int off = ((wr * 32 + m * 16 + lrow) << 5) + (lkc << 3);
      fka[m] = *(const bf16x8*)(kaT + off);
      fkb[m] = *(const bf16x8*)(kbT2 + off);
    }
    #pragma unroll
    for (int n = 0; n < 2; ++n) {
      const int off = ((wc * 32 + n * 16 + lrow) << 5) + (lkc << 3);
      fva[n] = *(const bf16x8*)(vaT + off);
      fvb[n] = *(const bf16x8*)(vbT2 + off);
    }
    #pragma unroll
    for (int m = 0; m < 2; ++m)
      #pragma unroll
      for (int n = 0; n < 2; ++n) {
        aAA[m][n] = __builtin_amdgcn_mfma_f32_16x16x32_bf16(fka[m], fva[n], aAA[m][n], 0, 0, 0);
        aBB[m][n] = __builtin_amdgcn_mfma_f32_16x16x32_bf16(fkb[m], fvb[n], aBB[m][n], 0, 0, 0);
        aAB[m][n] = __builtin_amdgcn_mfma_f32_16x16x32_bf16(fka[m], fvb[n], aAB[m][n], 0, 0, 0);
        aBA[m][n] = __builtin_amdgcn_mfma_f32_16x16x32_bf16(fkb[m], fva[n], aBA[m][n], 0, 0, 0);
      }
  }
  #pragma unroll
  for (int m = 0; m < 2; ++m)
    #pragma unroll
    for (int n = 0; n < 2; ++n) {
      const int row0 = wr * 32 + m * 16 + lkc * 4;
      const int col  = wc * 32 + n * 16 + lrow;
      #pragma unroll
      for (int r = 0; r < 4; ++r) {
        Eo[(long)h * 4096 + (row0 + r) * 64 + col]       = f2bf(SCALE * (aAA[m][n][r] - aBB[m][n][r]));
        Eo[(long)(8 + h) * 4096 + (row0 + r) * 64 + col] = f2bf(SCALE * (aAB[m][n][r] + aBA[m][n][r]));
      }
    }
}

// ---------------- bias vectors: cr = bq@(Fr-Fi) - 2bo ; ci = bq@(Fr+Fi) + 2bo ----------------
// wave-per-output-j: 64 lanes x 8 hd each, shuffle-reduce. grid 128 x 256.
__global__ __launch_bounds__(256)
void cvec_k(const float* __restrict__ FrT, const float* __restrict__ FiT,
            const float* __restrict__ bq, const float* __restrict__ bo, float* __restrict__ cv)
{
  const int j = blockIdx.x * 4 + (threadIdx.x >> 6);  // 0..511
  const int lane = threadIdx.x & 63;
  const float* fr = FrT + (long)j * HD + lane * 8;
  const float* fi = FiT + (long)j * HD + lane * 8;
  const float* bp = bq + lane * 8;
  f32x4 fr0 = ((const f32x4*)fr)[0], fr1 = ((const f32x4*)fr)[1];
  f32x4 fi0 = ((const f32x4*)fi)[0], fi1 = ((const f32x4*)fi)[1];
  f32x4 b0 = ((const f32x4*)bp)[0], b1 = ((const f32x4*)bp)[1];
  float sr = 0.f, si = 0.f;
  #pragma unroll
  for (int t = 0; t < 4; ++t) {
    sr += b0[t] * (fr0[t] - fi0[t]); si += b0[t] * (fr0[t] + fi0[t]);
    sr += b1[t] * (fr1[t] - fi1[t]); si += b1[t] * (fr1[t] + fi1[t]);
  }
  #pragma unroll
  for (int off = 32; off >= 1; off >>= 1) {
    sr += __shfl_xor(sr, off); si += __shfl_xor(si, off);
  }
  if (lane == 0) {
    cv[j]       = sr - 2.f * bo[j];
    cv[512 + j] = si + 2.f * bo[j];
  }
}

// ---------------- f32 [R,C] -> bf16 transpose, two scaled dests, depth-batched ----------------
__global__ __launch_bounds__(256)
void tcvt2_k(const float* __restrict__ in, short* __restrict__ d1, float s1,
             short* __restrict__ d2, float s2, int R, int C, int ldo,
             long inZ, long outZ)
{
  __shared__ float tile[32][33];
  in += (long)blockIdx.z * inZ;
  d1 += (long)blockIdx.z * outZ;
  if (d2) d2 += (long)blockIdx.z * outZ;
  const int bx = blockIdx.x * 32, by = blockIdx.y * 32;
  const int x = threadIdx.x & 31, y = threadIdx.x >> 5;
  #pragma unroll
  for (int j = 0; j < 32; j += 8)
    tile[y + j][x] = in[(long)(by + y + j) * C + bx + x];
  __syncthreads();
  #pragma unroll
  for (int j = 0; j < 32; j += 8) {
    const float v = tile[x][y + j];
    const long o = (long)(bx + y + j) * ldo + by + x;
    d1[o] = f2bf(s1 * v);
    if (d2) d2[o] = f2bf(s2 * v);
  }
}

// ---------------- flat f32 -> bf16 ----------------
__global__ __launch_bounds__(256)
void cvt_k(const float* __restrict__ in, short* __restrict__ out, int n)
{
  const int i = (blockIdx.x * 256 + threadIdx.x) * 4;
  if (i >= n) return;
  f32x4 v = *(const f32x4*)(in + i);
  short tmp[4] = {f2bf(v[0]), f2bf(v[1]), f2bf(v[2]), f2bf(v[3])};
  *(unsigned long long*)(out + i) = *(unsigned long long*)tmp;
}

extern "C" void kernel_launch(void* const* d_in, const int* in_sizes, int n_in,
                              void* d_out, int out_size, void* d_ws, size_t ws_size,
                              hipStream_t stream)
{
  const float* x_real = (const float*)d_in[0];
  const float* x_imag = (const float*)d_in[1];
  const float* Wq  = (const float*)d_in[2];
  const float* bq  = (const float*)d_in[3];
  const float* Wk  = (const float*)d_in[4];
  const float* bk  = (const float*)d_in[5];
  const float* Wv  = (const float*)d_in[6];
  const float* bv  = (const float*)d_in[7];
  const float* pk  = (const float*)d_in[8];
  const float* pv  = (const float*)d_in[9];
  const float* Wo  = (const float*)d_in[10];
  const float* bo  = (const float*)d_in[11];
  const float* W1r = (const float*)d_in[12];
  const float* W1i = (const float*)d_in[13];
  const float* b1r = (const float*)d_in[14];
  const float* b1i = (const float*)d_in[15];
  const float* W2r = (const float*)d_in[16];
  const float* W2i = (const float*)d_in[17];
  const float* b2r = (const float*)d_in[18];
  const float* b2i = (const float*)d_in[19];

  float* xr = (float*)d_out;
  float* xi = xr + (long)NSEQ * DM;
  const int BIG = 1 << 30;
  const long XIOFF = (long)NSEQ * DM - 512;   // col-split offset xr->xi

  char* base = (char*)d_ws;
  size_t off = 0;
  auto alloc = [&](size_t bytes) -> char* {
    char* p = base + off; off += (bytes + 255) & ~(size_t)255; return p;
  };

  // weights (both depths in one buffer; depth stride noted)
  short* wkvT = (short*)alloc((size_t)2 * 1024 * 512 * 2);   // [1024,512], dZ=524288
  short* woT  = (short*)alloc((size_t)2 * DM * HD * 2);      // dZ=262144
  short* wqB  = (short*)alloc((size_t)2 * DM * HD * 2);
  short* w1c  = (short*)alloc((size_t)2 * 4096 * 1024 * 2);  // [4096,1024], dZ=4194304
  short* w2c  = (short*)alloc((size_t)2 * 1024 * 4096 * 2);  // [1024,4096], dZ=4194304
  short* pkT  = (short*)alloc((size_t)2 * KLR * NSEQ * 2);   // dZ=1048576
  short* pvT  = (short*)alloc((size_t)2 * KLR * NSEQ * 2);
  float* bkvcat = (float*)alloc((size_t)2 * 1024 * 4);
  float* b1cat  = (float*)alloc((size_t)2 * 4096 * 4);
  float* b2cat  = (float*)alloc((size_t)2 * 1024 * 4);
  // activations
  short* ncat  = (short*)alloc((size_t)NSEQ * 2 * DM * 2);
  short* kvbT  = (short*)alloc((size_t)1024 * 2 * NSEQ * 2); // rows 0-511 k, 512-1023 v
  float* kvf   = (float*)alloc((size_t)4 * KLR * HD * 4);
  short* Eo    = (short*)alloc((size_t)16 * 64 * 64 * 2);
  float* FrT   = (float*)alloc((size_t)DM * HD * 4);
  float* FiT   = (float*)alloc((size_t)DM * HD * 4);
  short* FGb   = (short*)alloc((size_t)2 * DM * HD * 2);     // FrTb | FiTb contiguous
  short* BarBai= (short*)alloc((size_t)1024 * 1024 * 2);     // rows 0-511 Bar, 512-1023 Bai
  float* cv    = (float*)alloc((size_t)1024 * 4);
  short* hcat  = (short*)alloc((size_t)NSEQ * 2 * DFF * 2);  // [4096,4096]
  if (off > ws_size) return;

  hipMemcpyAsync(xr, x_real, (size_t)NSEQ * DM * 4, hipMemcpyDeviceToDevice, stream);
  hipMemcpyAsync(xi, x_imag, (size_t)NSEQ * DM * 4, hipMemcpyDeviceToDevice, stream);

  // ---- one-time weight prep (depth-batched z=2) ----
  tcvt2_k<<<dim3(HD/32, DM/32, 2), 256, 0, stream>>>(Wk, wkvT, 1.f, nullptr, 0.f, DM, HD, DM, (long)DM*HD, 524288);
  tcvt2_k<<<dim3(HD/32, DM/32, 2), 256, 0, stream>>>(Wv, wkvT + 512*512, 1.f, nullptr, 0.f, DM, HD, DM, (long)DM*HD, 524288);
  tcvt2_k<<<dim3(DM/32, HD/32, 2), 256, 0, stream>>>(Wo, woT, 1.f, nullptr, 0.f, HD, DM, HD, (long)HD*DM, 262144);
  cvt_k<<<2*DM*HD/1024, 256, 0, stream>>>(Wq, wqB, 2*DM*HD);
  tcvt2_k<<<dim3(DFF/32, DM/32, 2), 256, 0, stream>>>(W1r, w1c, 1.f, w1c + 2048*1024 + DM, 1.f, DM, DFF, 1024, (long)DM*DFF, 4194304);
  tcvt2_k<<<dim3(DFF/32, DM/32, 2), 256, 0, stream>>>(W1i, w1c + DM, -1.f, w1c + 2048*1024, 1.f, DM, DFF, 1024, (long)DM*DFF, 4194304);
  tcvt2_k<<<dim3(DM/32, DFF/32, 2), 256, 0, stream>>>(W2r, w2c, 1.f, w2c + 512*4096 + DFF, 1.f, DFF, DM, 4096, (long)DFF*DM, 4194304);
  tcvt2_k<<<dim3(DM/32, DFF/32, 2), 256, 0, stream>>>(W2i, w2c + DFF, -1.f, w2c + 512*4096, 1.f, DFF, DM, 4096, (long)DFF*DM, 4194304);
  tcvt2_k<<<dim3(KLR/32, NSEQ/32, 2), 256, 0, stream>>>(pk, pkT, 1.f, nullptr, 0.f, NSEQ, KLR, NSEQ, (long)NSEQ*KLR, 1048576);
  tcvt2_k<<<dim3(KLR/32, NSEQ/32, 2), 256, 0, stream>>>(pv, pvT, 1.f, nullptr, 0.f, NSEQ, KLR, NSEQ, (long)NSEQ*KLR, 1048576);
  for (int d = 0; d < 2; ++d) {
    hipMemcpyAsync(bkvcat + d*1024,       bk + d*HD,  HD*4,  hipMemcpyDeviceToDevice, stream);
    hipMemcpyAsync(bkvcat + d*1024 + 512, bv + d*HD,  HD*4,  hipMemcpyDeviceToDevice, stream);
    hipMemcpyAsync(b1cat + d*4096,        b1r + d*DFF, DFF*4, hipMemcpyDeviceToDevice, stream);
    hipMemcpyAsync(b1cat + d*4096 + 2048, b1i + d*DFF, DFF*4, hipMemcpyDeviceToDevice, stream);
    hipMemcpyAsync(b2cat + d*1024,        b2r + d*DM,  DM*4,  hipMemcpyDeviceToDevice, stream);
    hipMemcpyAsync(b2cat + d*1024 + 512,  b2i + d*DM,  DM*4,  hipMemcpyDeviceToDevice, stream);
  }

  for (int d = 0; d < 2; ++d) {
    const short* wkvT_d = wkvT + (long)d * 524288;
    const short* woT_d  = woT  + (long)d * 262144;
    const short* wqB_d  = wqB  + (long)d * 262144;
    const short* w1c_d  = w1c  + (long)d * 4194304;
    const short* w2c_d  = w2c  + (long)d * 4194304;
    const short* pkT_d  = pkT  + (long)d * 1048576;
    const short* pvT_d  = pvT  + (long)d * 1048576;
    const float* bq_d = bq + d * HD;   const float* bo_d = bo + d * DM;
    short* vbT = kvbT + (long)512 * 2 * NSEQ;

    // ---- attention ----
    cln_k<<<NSEQ/4, 256, 0, stream>>>(xr, xi, ncat);

    // merged k|v projection: kvbT[row, half*N + n], rows 0-511=k, 512-1023=v
    gemm_f<128,128,false><<<dim3(8, 32, 2), 256, 0, stream>>>(
      wkvT_d, 512, 0, ncat, 2*DM, DM, nullptr, 0, 0,
      kvbT, 2*NSEQ, NSEQ, nullptr, 0, 0,
      bkvcat + d*1024, 1.f, 1, 512, 1.f, 0.f, 0, 0, BIG, 0, 1);

    // keys/vals = pk^T k, pv^T v  (split-K, half=bz%2, kc=bz/2)
    hipMemsetAsync(kvf, 0, (size_t)4 * KLR * HD * 4, stream);
    gemm_f<128,128,true><<<dim3(2, 4, 32), 256, 0, stream>>>(
      pkT_d, NSEQ, 0, kvbT, 2*NSEQ, NSEQ, kvf, HD, (long)KLR*HD,
      nullptr, 0, 0, nullptr, 0, 0,
      nullptr, 0.f, 0, 256, 1.f, 0.f, 0, 0, BIG, 0, 2);
    gemm_f<128,128,true><<<dim3(2, 4, 32), 256, 0, stream>>>(
      pvT_d, NSEQ, 0, vbT, 2*NSEQ, NSEQ, kvf + 2L*KLR*HD, HD, (long)KLR*HD,
      nullptr, 0, 0, nullptr, 0, 0,
      nullptr, 0.f, 0, 256, 1.f, 0.f, 0, 0, BIG, 0, 2);

    // per-head 64x64 E matrices
    e_k<<<8, 256, 0, stream>>>(kvf, Eo);

    // F = E @ Wo (batched per head); bf16 copies into FGb (Fr | Fi)
    gemm_f<128,64,false><<<dim3(4, 1, 8), 256, 0, stream>>>(
      woT_d, HD, 64, Eo, 64, 4096, FrT, DM, 64, FGb, DM, 64,
      nullptr, 0, 0, nullptr, 0.f, 0, 64, 1.f, 0.f, 0, 1, BIG, 0, 1);
    gemm_f<128,64,false><<<dim3(4, 1, 8), 256, 0, stream>>>(
      woT_d, HD, 64, Eo + 8L*4096, 64, 4096, FiT, DM, 64, FGb + 262144, DM, 64,
      nullptr, 0, 0, nullptr, 0.f, 0, 64, 1.f, 0.f, 0, 1, BIG, 0, 1);

    // merged G: z=0 Fr -> Bar rows + Bai cols512.. ; z=1 Fi -> Bai rows + (-)Bar cols512..
    gemm_f<128,128,false><<<dim3(4, 4, 2), 256, 0, stream>>>(
      FGb, HD, 262144, wqB_d, HD, 0, nullptr, 0, 0,
      BarBai, 2*DM, 524288, BarBai + 524288 + DM, -524288L, 2,
      nullptr, 0.f, 0, HD, 1.f, 0.f, 0, 0, BIG, 0, 1);

    cvec_k<<<128, 256, 0, stream>>>(FrT, FiT, bq_d, bo_d, cv);

    // merged apply (split-K=2, atomic into xr/xi, bias at kc==0)
    gemm_f<128,128,true><<<dim3(32, 8, 2), 256, 0, stream>>>(
      ncat, 2*DM, 0, BarBai, 2*DM, 0, xr, DM, 0,
      nullptr, 0, 0, nullptr, 0, 0,
      cv, 1.f, 0, 512, 1.f, 0.f, 0, 0, 512, XIOFF, 1);

    // ---- FFN ----
    cln_k<<<NSEQ/4, 256, 0, stream>>>(xr, xi, ncat);

    // merged FFN1: N=4096 (hr cols 0-2047, hi cols 2048-4095 -> hcat)
    gemm_f<128,128,false><<<dim3(32, 32, 1), 256, 0, stream>>>(
      ncat, 2*DM, 0, w1c_d, 2*DM, 0, nullptr, 0, 0, hcat, 2*DFF, 0,
      nullptr, 0, 0, b1cat + d*4096, 1.f, 0, 1024, 1.f, 0.f, 1, 0, BIG, 0, 1);

    // merged FFN2 (split-K=2, atomic into xr/xi, bias at kc==0)
    gemm_f<128,128,true><<<dim3(32, 8, 2), 256, 0, stream>>>(
      hcat, 2*DFF, 0, w2c_d, 2*DFF, 0, xr, DM, 0,
      nullptr, 0, 0, nullptr, 0, 0,
      b2cat + d*1024, 1.f, 0, 2048, 1.f, 0.f, 0, 0, 512, XIOFF, 1);
  }
}

// Round 10
// 836.213 us; speedup vs baseline: 1.9222x; 1.0195x over previous
//
#include <hip/hip_runtime.h>

#define NSEQ 4096
#define DM   512
#define KLR  256
#define HD   512   // H*DH
#define DFF  2048
#define SCALE 0.125f

typedef __attribute__((ext_vector_type(4))) float  f32x4;
typedef __attribute__((ext_vector_type(8))) short  short8;
typedef __attribute__((ext_vector_type(8))) __bf16 bf16x8;

__device__ __forceinline__ short f2bf(float f) {
  unsigned u = __float_as_uint(f);
  u = (u + 0x7fffu + ((u >> 16) & 1u)) >> 16;
  return (short)u;
}

__device__ __forceinline__ void gload_lds(const short* g, void* ldsbase) {
  __builtin_amdgcn_global_load_lds(
      (const __attribute__((address_space(1))) void*)g,
      (__attribute__((address_space(3))) void*)ldsbase, 16, 0, 0);
}

// ---------------- fast bf16 MFMA GEMM (m97 structure + 2-phase dbuf prefetch) ----------------
// C = alpha*A*B^T(+beta*Cf)(+bscale*bias)(relu). A [M,K] row-major bf16.
// B TRANSPOSED [N,K] row-major bf16. global_load_lds w=16 staging.
// K-loop: double-buffered LDS; next tile's loads issued BEFORE current tile's
// compute, one vmcnt(0)+barrier per step (T3 minimum-2-phase; hides load lat).
// Col-split epilogue: col >= colSplit -> Cf += csOff (merged xr/xi outputs).
// SK: half = bz%skH, kchunk = bz/skH; atomicAdd f32 (+bias once at kc==0).
// negMask: bit bz -> negate Cb2 write for that batch. sCb2 may be negative.
template<int BM, int BN, bool SK>
__global__ __launch_bounds__(256)
void gemm_f(const short* __restrict__ A, int lda, long sA,
            const short* __restrict__ B, int ldb, long sB,
            float* __restrict__ Cf, int ldc, long sCf,
            short* __restrict__ Cb, int ldcb, long sCb,
            short* __restrict__ Cb2, long sCb2, int negMask,
            const float* __restrict__ bias, float bscale, int rowBias,
            int Kd, float alpha, float beta, int relu, int writeCf,
            int colSplit, long csOff, int skH)
{
  constexpr int WM = BM / 2, WN = BN / 2, FM = WM / 16, FN = WN / 16;
  constexpr int AISS = (BM * 64) / 4096, BISS = (BN * 64) / 4096;
  const int tid = threadIdx.x, bz = blockIdx.z;
  long kbeg = 0;
  int kc = 0;
  if constexpr (SK) {
    const int half = bz % skH; kc = bz / skH;
    A += (long)half * sA; B += (long)half * sB; Cf += (long)half * sCf;
    kbeg = (long)kc * Kd;
  } else {
    A += (long)bz * sA; B += (long)bz * sB;
    Cf += (long)bz * sCf; Cb += (long)bz * sCb;
    if (Cb2) Cb2 += (long)bz * sCb2;
  }
  const int bm0 = blockIdx.x * BM, bn0 = blockIdx.y * BN;
  __shared__ __align__(16) short As[2][BM * 32];
  __shared__ __align__(16) short Bs[2][BN * 32];
  const int wid = tid >> 6, lane = tid & 63;
  const int wr = wid >> 1, wc = wid & 1;
  const int lrow = lane & 15, lkc = lane >> 4;

  f32x4 acc[FM][FN] = {};

  auto STAGE = [&](int buf, int kt) {
    const long kg = kbeg + ((long)kt << 5);
    #pragma unroll
    for (int i = 0; i < AISS; ++i) {
      const int fb = i * 4096 + wid * 1024;
      const int f = fb + lane * 16;
      const int r = f >> 6, e = (f & 63) >> 1;
      gload_lds(A + (long)(bm0 + r) * lda + kg + e, (char*)As[buf] + fb);
    }
    #pragma unroll
    for (int i = 0; i < BISS; ++i) {
      const int fb = i * 4096 + wid * 1024;
      const int f = fb + lane * 16;
      const int r = f >> 6, e = (f & 63) >> 1;
      gload_lds(B + (long)(bn0 + r) * ldb + kg + e, (char*)Bs[buf] + fb);
    }
  };

  auto COMPUTE = [&](int buf) {
    bf16x8 af[FM], bfv[FN];
    #pragma unroll
    for (int m = 0; m < FM; ++m)
      af[m] = *(const bf16x8*)(As[buf] + ((wr * WM + m * 16 + lrow) << 5) + (lkc << 3));
    #pragma unroll
    for (int n = 0; n < FN; ++n)
      bfv[n] = *(const bf16x8*)(Bs[buf] + ((wc * WN + n * 16 + lrow) << 5) + (lkc << 3));
    #pragma unroll
    for (int m = 0; m < FM; ++m)
      #pragma unroll
      for (int n = 0; n < FN; ++n)
        acc[m][n] = __builtin_amdgcn_mfma_f32_16x16x32_bf16(af[m], bfv[n], acc[m][n], 0, 0, 0);
  };

  const int nK = Kd >> 5;
  int cur = 0;
  STAGE(0, 0);
  __syncthreads();                 // drains vmcnt(0): tile 0 ready
  for (int kt = 0; kt < nK - 1; ++kt) {
    STAGE(cur ^ 1, kt + 1);        // issue next tile FIRST (overlaps with MFMA)
    COMPUTE(cur);
    __syncthreads();               // vmcnt(0)+barrier: next tile ready, buf reusable
    cur ^= 1;
  }
  COMPUTE(cur);                    // epilogue tile, no prefetch

  #pragma unroll
  for (int m = 0; m < FM; ++m) {
    #pragma unroll
    for (int n = 0; n < FN; ++n) {
      const int row0 = bm0 + wr * WM + m * 16 + lkc * 4;
      const int col  = bn0 + wc * WN + n * 16 + lrow;
      float* cfp = Cf + ((col >= colSplit) ? csOff : 0);
      #pragma unroll
      for (int r = 0; r < 4; ++r) {
        if constexpr (SK) {
          float v = alpha * acc[m][n][r];
          if (bias && kc == 0) v += bscale * bias[rowBias ? (row0 + r) : col];
          atomicAdd(cfp + (long)(row0 + r) * ldc + col, v);
        } else {
          float v = alpha * acc[m][n][r];
          if (beta != 0.f) v += beta * cfp[(long)(row0 + r) * ldc + col];
          if (bias) v += bscale * bias[rowBias ? (row0 + r) : col];
          if (relu) v = fmaxf(v, 0.f);
          if (writeCf) cfp[(long)(row0 + r) * ldc + col] = v;
          if (Cb)  Cb [(long)(row0 + r) * ldcb + col] = f2bf(v);
          if (Cb2) Cb2[(long)(row0 + r) * ldcb + col] = f2bf(((negMask >> bz) & 1) ? -v : v);
        }
      }
    }
  }
}

// ---------------- complex layernorm -> bf16 cat layout [N, 2*DM] ----------------
__global__ __launch_bounds__(256)
void cln_k(const float* __restrict__ xr, const float* __restrict__ xi, short* __restrict__ ncat)
{
  const int row  = blockIdx.x * 4 + (threadIdx.x >> 6);
  const int lane = threadIdx.x & 63;
  const float* pr = xr + (long)row * DM + lane * 8;
  const float* pi = xi + (long)row * DM + lane * 8;
  f32x4 a0 = ((const f32x4*)pr)[0], a1 = ((const f32x4*)pr)[1];
  f32x4 b0 = ((const f32x4*)pi)[0], b1 = ((const f32x4*)pi)[1];
  float ar[8], ai[8];
  #pragma unroll
  for (int j = 0; j < 4; ++j) { ar[j] = a0[j]; ar[4 + j] = a1[j]; ai[j] = b0[j]; ai[4 + j] = b1[j]; }
  float sr = 0, si = 0, srr = 0, sii = 0, sri = 0;
  #pragma unroll
  for (int j = 0; j < 8; ++j) {
    sr += ar[j]; si += ai[j];
    srr += ar[j] * ar[j]; sii += ai[j] * ai[j]; sri += ar[j] * ai[j];
  }
  #pragma unroll
  for (int off = 32; off >= 1; off >>= 1) {
    sr  += __shfl_xor(sr, off);  si  += __shfl_xor(si, off);
    srr += __shfl_xor(srr, off); sii += __shfl_xor(sii, off); sri += __shfl_xor(sri, off);
  }
  const float inv512 = 1.f / 512.f;
  float mr = sr * inv512, mi = si * inv512;
  float Crr = srr * inv512 - mr * mr + 1e-5f;
  float Cii = sii * inv512 - mi * mi + 1e-5f;
  float Cri = sri * inv512 - mr * mi;
  float s = sqrtf(fmaxf(Crr * Cii - Cri * Cri, 0.f));
  float t = sqrtf(Crr + Cii + 2.f * s);
  float inv = 1.f / (s * t);
  float Rrr = (Cii + s) * inv, Rii = (Crr + s) * inv, Rri = -Cri * inv;
  short8 vr, vi;
  #pragma unroll
  for (int j = 0; j < 8; ++j) {
    float a = ar[j] - mr, b = ai[j] - mi;
    vr[j] = f2bf(Rrr * a + Rri * b);
    vi[j] = f2bf(Rii * b + Rri * a);
  }
  *(short8*)(ncat + (long)row * (2 * DM) + lane * 8) = vr;
  *(short8*)(ncat + (long)row * (2 * DM) + DM + lane * 8) = vi;
}

// ---------------- per-head E = SC*(kA^T vA - kB^T vB), Ei = SC*(kB^T vA + kA^T vB) ----------------
__global__ __launch_bounds__(256)
void e_k(const float* __restrict__ kvf, short* __restrict__ Eo)
{
  const int h = blockIdx.x;
  const int tid = threadIdx.x;
  const int wid = tid >> 6, lane = tid & 63;
  const int wr = wid >> 1, wc = wid & 1;
  const int lrow = lane & 15, lkc = lane >> 4;
  __shared__ short kaT[64 * 32], kbT2[64 * 32], vaT[64 * 32], vbT2[64 * 32];
  const float* kA = kvf + (long)h * 64;
  const float* kB = kA + (long)KLR * HD;
  const float* vA = kB + (long)KLR * HD;
  const float* vB = vA + (long)KLR * HD;
  f32x4 aAA[2][2] = {}, aBB[2][2] = {}, aAB[2][2] = {}, aBA[2][2] = {};
  const int kr = tid >> 3;
  const int dh0 = (tid & 7) * 8;
  for (int kt = 0; kt < 8; ++kt) {
    __syncthreads();
    const long krow = kt * 32 + kr;
    #pragma unroll
    for (int j = 0; j < 8; ++j) {
      const int dh = dh0 + j;
      kaT [dh * 32 + kr] = f2bf(kA[krow * HD + dh]);
      kbT2[dh * 32 + kr] = f2bf(kB[krow * HD + dh]);
      vaT [dh * 32 + kr] = f2bf(vA[krow * HD + dh]);
      vbT2[dh * 32 + kr] = f2bf(vB[krow * HD + dh]);
    }
    __syncthreads();
    bf16x8 fka[2], fkb[2], fva[2], fvb[2];
    #pragma unroll
    for (int m = 0; m < 2; ++m) {
      const int off = ((wr * 32 + m * 16 + lrow) << 5) + (lkc << 3);
      fka[m] = *(const bf16x8*)(kaT + off);
      fkb[m] = *(const bf16x8*)(kbT2 + off);
    }
    #pragma unroll
    for (int n = 0; n < 2; ++n) {
      const int off = ((wc * 32 + n * 16 + lrow) << 5) + (lkc << 3);
      fva[n] = *(const bf16x8*)(vaT + off);
      fvb[n] = *(const bf16x8*)(vbT2 + off);
    }
    #pragma unroll
    for (int m = 0; m < 2; ++m)
      #pragma unroll
      for (int n = 0; n < 2; ++n) {
        aAA[m][n] = __builtin_amdgcn_mfma_f32_16x16x32_bf16(fka[m], fva[n], aAA[m][n], 0, 0, 0);
        aBB[m][n] = __builtin_amdgcn_mfma_f32_16x16x32_bf16(fkb[m], fvb[n], aBB[m][n], 0, 0, 0);
        aAB[m][n] = __builtin_amdgcn_mfma_f32_16x16x32_bf16(fka[m], fvb[n], aAB[m][n], 0, 0, 0);
        aBA[m][n] = __builtin_amdgcn_mfma_f32_16x16x32_bf16(fkb[m], fva[n], aBA[m][n], 0, 0, 0);
      }
  }
  #pragma unroll
  for (int m = 0; m < 2; ++m)
    #pragma unroll
    for (int n = 0; n < 2; ++n) {
      const int row0 = wr * 32 + m * 16 + lkc * 4;
      const int col  = wc * 32 + n * 16 + lrow;
      #pragma unroll
      for (int r = 0; r < 4; ++r) {
        Eo[(long)h * 4096 + (row0 + r) * 64 + col]       = f2bf(SCALE * (aAA[m][n][r] - aBB[m][n][r]));
        Eo[(long)(8 + h) * 4096 + (row0 + r) * 64 + col] = f2bf(SCALE * (aAB[m][n][r] + aBA[m][n][r]));
      }
    }
}

// ---------------- bias vectors: cr = bq@(Fr-Fi) - 2bo ; ci = bq@(Fr+Fi) + 2bo ----------------
// wave-per-output-j: 64 lanes x 8 hd each, shuffle-reduce. grid 128 x 256.
__global__ __launch_bounds__(256)
void cvec_k(const float* __restrict__ FrT, const float* __restrict__ FiT,
            const float* __restrict__ bq, const float* __restrict__ bo, float* __restrict__ cv)
{
  const int j = blockIdx.x * 4 + (threadIdx.x >> 6);  // 0..511
  const int lane = threadIdx.x & 63;
  const float* fr = FrT + (long)j * HD + lane * 8;
  const float* fi = FiT + (long)j * HD + lane * 8;
  const float* bp = bq + lane * 8;
  f32x4 fr0 = ((const f32x4*)fr)[0], fr1 = ((const f32x4*)fr)[1];
  f32x4 fi0 = ((const f32x4*)fi)[0], fi1 = ((const f32x4*)fi)[1];
  f32x4 b0 = ((const f32x4*)bp)[0], b1 = ((const f32x4*)bp)[1];
  float sr = 0.f, si = 0.f;
  #pragma unroll
  for (int t = 0; t < 4; ++t) {
    sr += b0[t] * (fr0[t] - fi0[t]); si += b0[t] * (fr0[t] + fi0[t]);
    sr += b1[t] * (fr1[t] - fi1[t]); si += b1[t] * (fr1[t] + fi1[t]);
  }
  #pragma unroll
  for (int off = 32; off >= 1; off >>= 1) {
    sr += __shfl_xor(sr, off); si += __shfl_xor(si, off);
  }
  if (lane == 0) {
    cv[j]       = sr - 2.f * bo[j];
    cv[512 + j] = si + 2.f * bo[j];
  }
}

// ---------------- f32 [R,C] -> bf16 transpose, two scaled dests, depth-batched ----------------
__global__ __launch_bounds__(256)
void tcvt2_k(const float* __restrict__ in, short* __restrict__ d1, float s1,
             short* __restrict__ d2, float s2, int R, int C, int ldo,
             long inZ, long outZ)
{
  __shared__ float tile[32][33];
  in += (long)blockIdx.z * inZ;
  d1 += (long)blockIdx.z * outZ;
  if (d2) d2 += (long)blockIdx.z * outZ;
  const int bx = blockIdx.x * 32, by = blockIdx.y * 32;
  const int x = threadIdx.x & 31, y = threadIdx.x >> 5;
  #pragma unroll
  for (int j = 0; j < 32; j += 8)
    tile[y + j][x] = in[(long)(by + y + j) * C + bx + x];
  __syncthreads();
  #pragma unroll
  for (int j = 0; j < 32; j += 8) {
    const float v = tile[x][y + j];
    const long o = (long)(bx + y + j) * ldo + by + x;
    d1[o] = f2bf(s1 * v);
    if (d2) d2[o] = f2bf(s2 * v);
  }
}

// ---------------- flat f32 -> bf16 ----------------
__global__ __launch_bounds__(256)
void cvt_k(const float* __restrict__ in, short* __restrict__ out, int n)
{
  const int i = (blockIdx.x * 256 + threadIdx.x) * 4;
  if (i >= n) return;
  f32x4 v = *(const f32x4*)(in + i);
  short tmp[4] = {f2bf(v[0]), f2bf(v[1]), f2bf(v[2]), f2bf(v[3])};
  *(unsigned long long*)(out + i) = *(unsigned long long*)tmp;
}

extern "C" void kernel_launch(void* const* d_in, const int* in_sizes, int n_in,
                              void* d_out, int out_size, void* d_ws, size_t ws_size,
                              hipStream_t stream)
{
  const float* x_real = (const float*)d_in[0];
  const float* x_imag = (const float*)d_in[1];
  const float* Wq  = (const float*)d_in[2];
  const float* bq  = (const float*)d_in[3];
  const float* Wk  = (const float*)d_in[4];
  const float* bk  = (const float*)d_in[5];
  const float* Wv  = (const float*)d_in[6];
  const float* bv  = (const float*)d_in[7];
  const float* pk  = (const float*)d_in[8];
  const float* pv  = (const float*)d_in[9];
  const float* Wo  = (const float*)d_in[10];
  const float* bo  = (const float*)d_in[11];
  const float* W1r = (const float*)d_in[12];
  const float* W1i = (const float*)d_in[13];
  const float* b1r = (const float*)d_in[14];
  const float* b1i = (const float*)d_in[15];
  const float* W2r = (const float*)d_in[16];
  const float* W2i = (const float*)d_in[17];
  const float* b2r = (const float*)d_in[18];
  const float* b2i = (const float*)d_in[19];

  float* xr = (float*)d_out;
  float* xi = xr + (long)NSEQ * DM;
  const int BIG = 1 << 30;
  const long XIOFF = (long)NSEQ * DM - 512;   // col-split offset xr->xi

  char* base = (char*)d_ws;
  size_t off = 0;
  auto alloc = [&](size_t bytes) -> char* {
    char* p = base + off; off += (bytes + 255) & ~(size_t)255; return p;
  };

  // weights (both depths in one buffer; depth stride noted)
  short* wkvT = (short*)alloc((size_t)2 * 1024 * 512 * 2);   // [1024,512], dZ=524288
  short* woT  = (short*)alloc((size_t)2 * DM * HD * 2);      // dZ=262144
  short* wqB  = (short*)alloc((size_t)2 * DM * HD * 2);
  short* w1c  = (short*)alloc((size_t)2 * 4096 * 1024 * 2);  // [4096,1024], dZ=4194304
  short* w2c  = (short*)alloc((size_t)2 * 1024 * 4096 * 2);  // [1024,4096], dZ=4194304
  short* pkT  = (short*)alloc((size_t)2 * KLR * NSEQ * 2);   // dZ=1048576
  short* pvT  = (short*)alloc((size_t)2 * KLR * NSEQ * 2);
  float* bkvcat = (float*)alloc((size_t)2 * 1024 * 4);
  float* b1cat  = (float*)alloc((size_t)2 * 4096 * 4);
  float* b2cat  = (float*)alloc((size_t)2 * 1024 * 4);
  // activations
  short* ncat  = (short*)alloc((size_t)NSEQ * 2 * DM * 2);
  short* kvbT  = (short*)alloc((size_t)1024 * 2 * NSEQ * 2); // rows 0-511 k, 512-1023 v
  float* kvf   = (float*)alloc((size_t)4 * KLR * HD * 4);
  short* Eo    = (short*)alloc((size_t)16 * 64 * 64 * 2);
  float* FrT   = (float*)alloc((size_t)DM * HD * 4);
  float* FiT   = (float*)alloc((size_t)DM * HD * 4);
  short* FGb   = (short*)alloc((size_t)2 * DM * HD * 2);     // FrTb | FiTb contiguous
  short* BarBai= (short*)alloc((size_t)1024 * 1024 * 2);     // rows 0-511 Bar, 512-1023 Bai
  float* cv    = (float*)alloc((size_t)1024 * 4);
  short* hcat  = (short*)alloc((size_t)NSEQ * 2 * DFF * 2);  // [4096,4096]
  if (off > ws_size) return;

  hipMemcpyAsync(xr, x_real, (size_t)NSEQ * DM * 4, hipMemcpyDeviceToDevice, stream);
  hipMemcpyAsync(xi, x_imag, (size_t)NSEQ * DM * 4, hipMemcpyDeviceToDevice, stream);

  // ---- one-time weight prep (depth-batched z=2) ----
  tcvt2_k<<<dim3(HD/32, DM/32, 2), 256, 0, stream>>>(Wk, wkvT, 1.f, nullptr, 0.f, DM, HD, DM, (long)DM*HD, 524288);
  tcvt2_k<<<dim3(HD/32, DM/32, 2), 256, 0, stream>>>(Wv, wkvT + 512*512, 1.f, nullptr, 0.f, DM, HD, DM, (long)DM*HD, 524288);
  tcvt2_k<<<dim3(DM/32, HD/32, 2), 256, 0, stream>>>(Wo, woT, 1.f, nullptr, 0.f, HD, DM, HD, (long)HD*DM, 262144);
  cvt_k<<<2*DM*HD/1024, 256, 0, stream>>>(Wq, wqB, 2*DM*HD);
  tcvt2_k<<<dim3(DFF/32, DM/32, 2), 256, 0, stream>>>(W1r, w1c, 1.f, w1c + 2048*1024 + DM, 1.f, DM, DFF, 1024, (long)DM*DFF, 4194304);
  tcvt2_k<<<dim3(DFF/32, DM/32, 2), 256, 0, stream>>>(W1i, w1c + DM, -1.f, w1c + 2048*1024, 1.f, DM, DFF, 1024, (long)DM*DFF, 4194304);
  tcvt2_k<<<dim3(DM/32, DFF/32, 2), 256, 0, stream>>>(W2r, w2c, 1.f, w2c + 512*4096 + DFF, 1.f, DFF, DM, 4096, (long)DFF*DM, 4194304);
  tcvt2_k<<<dim3(DM/32, DFF/32, 2), 256, 0, stream>>>(W2i, w2c + DFF, -1.f, w2c + 512*4096, 1.f, DFF, DM, 4096, (long)DFF*DM, 4194304);
  tcvt2_k<<<dim3(KLR/32, NSEQ/32, 2), 256, 0, stream>>>(pk, pkT, 1.f, nullptr, 0.f, NSEQ, KLR, NSEQ, (long)NSEQ*KLR, 1048576);
  tcvt2_k<<<dim3(KLR/32, NSEQ/32, 2), 256, 0, stream>>>(pv, pvT, 1.f, nullptr, 0.f, NSEQ, KLR, NSEQ, (long)NSEQ*KLR, 1048576);
  for (int d = 0; d < 2; ++d) {
    hipMemcpyAsync(bkvcat + d*1024,       bk + d*HD,  HD*4,  hipMemcpyDeviceToDevice, stream);
    hipMemcpyAsync(bkvcat + d*1024 + 512, bv + d*HD,  HD*4,  hipMemcpyDeviceToDevice, stream);
    hipMemcpyAsync(b1cat + d*4096,        b1r + d*DFF, DFF*4, hipMemcpyDeviceToDevice, stream);
    hipMemcpyAsync(b1cat + d*4096 + 2048, b1i + d*DFF, DFF*4, hipMemcpyDeviceToDevice, stream);
    hipMemcpyAsync(b2cat + d*1024,        b2r + d*DM,  DM*4,  hipMemcpyDeviceToDevice, stream);
    hipMemcpyAsync(b2cat + d*1024 + 512,  b2i + d*DM,  DM*4,  hipMemcpyDeviceToDevice, stream);
  }

  for (int d = 0; d < 2; ++d) {
    const short* wkvT_d = wkvT + (long)d * 524288;
    const short* woT_d  = woT  + (long)d * 262144;
    const short* wqB_d  = wqB  + (long)d * 262144;
    const short* w1c_d  = w1c  + (long)d * 4194304;
    const short* w2c_d  = w2c  + (long)d * 4194304;
    const short* pkT_d  = pkT  + (long)d * 1048576;
    const short* pvT_d  = pvT  + (long)d * 1048576;
    const float* bq_d = bq + d * HD;   const float* bo_d = bo + d * DM;
    short* vbT = kvbT + (long)512 * 2 * NSEQ;

    // ---- attention ----
    cln_k<<<NSEQ/4, 256, 0, stream>>>(xr, xi, ncat);

    // merged k|v projection: kvbT[row, half*N + n], rows 0-511=k, 512-1023=v
    gemm_f<128,128,false><<<dim3(8, 32, 2), 256, 0, stream>>>(
      wkvT_d, 512, 0, ncat, 2*DM, DM, nullptr, 0, 0,
      kvbT, 2*NSEQ, NSEQ, nullptr, 0, 0,
      bkvcat + d*1024, 1.f, 1, 512, 1.f, 0.f, 0, 0, BIG, 0, 1);

    // keys/vals = pk^T k, pv^T v  (split-K, half=bz%2, kc=bz/2)
    hipMemsetAsync(kvf, 0, (size_t)4 * KLR * HD * 4, stream);
    gemm_f<128,128,true><<<dim3(2, 4, 32), 256, 0, stream>>>(
      pkT_d, NSEQ, 0, kvbT, 2*NSEQ, NSEQ, kvf, HD, (long)KLR*HD,
      nullptr, 0, 0, nullptr, 0, 0,
      nullptr, 0.f, 0, 256, 1.f, 0.f, 0, 0, BIG, 0, 2);
    gemm_f<128,128,true><<<dim3(2, 4, 32), 256, 0, stream>>>(
      pvT_d, NSEQ, 0, vbT, 2*NSEQ, NSEQ, kvf + 2L*KLR*HD, HD, (long)KLR*HD,
      nullptr, 0, 0, nullptr, 0, 0,
      nullptr, 0.f, 0, 256, 1.f, 0.f, 0, 0, BIG, 0, 2);

    // per-head 64x64 E matrices
    e_k<<<8, 256, 0, stream>>>(kvf, Eo);

    // F = E @ Wo (batched per head); bf16 copies into FGb (Fr | Fi)
    gemm_f<128,64,false><<<dim3(4, 1, 8), 256, 0, stream>>>(
      woT_d, HD, 64, Eo, 64, 4096, FrT, DM, 64, FGb, DM, 64,
      nullptr, 0, 0, nullptr, 0.f, 0, 64, 1.f, 0.f, 0, 1, BIG, 0, 1);
    gemm_f<128,64,false><<<dim3(4, 1, 8), 256, 0, stream>>>(
      woT_d, HD, 64, Eo + 8L*4096, 64, 4096, FiT, DM, 64, FGb + 262144, DM, 64,
      nullptr, 0, 0, nullptr, 0.f, 0, 64, 1.f, 0.f, 0, 1, BIG, 0, 1);

    // merged G: z=0 Fr -> Bar rows + Bai cols512.. ; z=1 Fi -> Bai rows + (-)Bar cols512..
    gemm_f<128,128,false><<<dim3(4, 4, 2), 256, 0, stream>>>(
      FGb, HD, 262144, wqB_d, HD, 0, nullptr, 0, 0,
      BarBai, 2*DM, 524288, BarBai + 524288 + DM, -524288L, 2,
      nullptr, 0.f, 0, HD, 1.f, 0.f, 0, 0, BIG, 0, 1);

    cvec_k<<<128, 256, 0, stream>>>(FrT, FiT, bq_d, bo_d, cv);

    // merged apply (split-K=2, atomic into xr/xi, bias at kc==0)
    gemm_f<128,128,true><<<dim3(32, 8, 2), 256, 0, stream>>>(
      ncat, 2*DM, 0, BarBai, 2*DM, 0, xr, DM, 0,
      nullptr, 0, 0, nullptr, 0, 0,
      cv, 1.f, 0, 512, 1.f, 0.f, 0, 0, 512, XIOFF, 1);

    // ---- FFN ----
    cln_k<<<NSEQ/4, 256, 0, stream>>>(xr, xi, ncat);

    // merged FFN1: N=4096 (hr cols 0-2047, hi cols 2048-4095 -> hcat)
    gemm_f<128,128,false><<<dim3(32, 32, 1), 256, 0, stream>>>(
      ncat, 2*DM, 0, w1c_d, 2*DM, 0, nullptr, 0, 0, hcat, 2*DFF, 0,
      nullptr, 0, 0, b1cat + d*4096, 1.f, 0, 1024, 1.f, 0.f, 1, 0, BIG, 0, 1);

    // merged FFN2 (split-K=2, atomic into xr/xi, bias at kc==0)
    gemm_f<128,128,true><<<dim3(32, 8, 2), 256, 0, stream>>>(
      hcat, 2*DFF, 0, w2c_d, 2*DFF, 0, xr, DM, 0,
      nullptr, 0, 0, nullptr, 0, 0,
      b2cat + d*1024, 1.f, 0, 2048, 1.f, 0.f, 0, 0, 512, XIOFF, 1);
  }
}